// Round 1
// baseline (2549.376 us; speedup 1.0000x reference)
//
#include <hip/hip_runtime.h>
#include <cmath>

// EVRP solver rollout — full decode on-device, one block per batch element.
// PRNG: JAX threefry2x32. Variant 0 = partitionable (bits1^bits2), the default
// in modern JAX. 1 = partitionable bits1-only. 2 = original iota-halves.
#define PRNG_VARIANT 0

#define BSZ 256
#define SEQN 256
#define HD 128
#define NG 512
#define NEGV -1000000000.0f
#define TINYF 1.17549435e-38f

static __device__ __forceinline__ void tf2x32(unsigned k0, unsigned k1,
                                              unsigned x0, unsigned x1,
                                              unsigned &o0, unsigned &o1) {
  unsigned ks2 = k0 ^ k1 ^ 0x1BD11BDAu;
#define TFR(r) { x0 += x1; x1 = (x1 << (r)) | (x1 >> (32 - (r))); x1 ^= x0; }
  x0 += k0; x1 += k1;
  TFR(13) TFR(15) TFR(26) TFR(6)
  x0 += k1; x1 += ks2 + 1u;
  TFR(17) TFR(29) TFR(16) TFR(24)
  x0 += ks2; x1 += k0 + 2u;
  TFR(13) TFR(15) TFR(26) TFR(6)
  x0 += k0; x1 += k1 + 3u;
  TFR(17) TFR(29) TFR(16) TFR(24)
  x0 += k1; x1 += ks2 + 4u;
  TFR(13) TFR(15) TFR(26) TFR(6)
  x0 += ks2; x1 += k0 + 5u;
#undef TFR
  o0 = x0; o1 = x1;
}

// keys = jax.random.split(jax.random.key(1), T); key data of key(1) is (0,1).
static __device__ __forceinline__ void step_key(int t, unsigned &k0, unsigned &k1) {
#if PRNG_VARIANT == 2
  // original: out = threefry((0,1), iota(2T)) via halves; keys[t]=(out[2t],out[2t+1])
  unsigned a0, a1, b0, b1;
  if (t < 64) {
    tf2x32(0u, 1u, (unsigned)(2 * t),     (unsigned)(128 + 2 * t), a0, a1);
    tf2x32(0u, 1u, (unsigned)(2 * t + 1), (unsigned)(129 + 2 * t), b0, b1);
    k0 = a0; k1 = b0;
  } else {
    tf2x32(0u, 1u, (unsigned)(2 * t - 128), (unsigned)(2 * t),     a0, a1);
    tf2x32(0u, 1u, (unsigned)(2 * t - 127), (unsigned)(2 * t + 1), b0, b1);
    k0 = a1; k1 = b1;
  }
#else
  // partitionable/foldlike: keys[t] = threefry((0,1), (0, t))
  tf2x32(0u, 1u, 0u, (unsigned)t, k0, k1);
#endif
}

static __device__ __forceinline__ unsigned rand_bits32(unsigned k0, unsigned k1, int flat) {
#if PRNG_VARIANT == 2
  unsigned o0, o1;
  if (flat < 32768) { tf2x32(k0, k1, (unsigned)flat, (unsigned)(flat + 32768), o0, o1); return o0; }
  else              { tf2x32(k0, k1, (unsigned)(flat - 32768), (unsigned)flat, o0, o1); return o1; }
#else
  unsigned o0, o1;
  tf2x32(k0, k1, 0u, (unsigned)flat, o0, o1);
#if PRNG_VARIANT == 0
  return o0 ^ o1;
#else
  return o0;
#endif
#endif
}

__global__ __launch_bounds__(512, 2) void evrp_kernel(
    const float* __restrict__ statc, const float* __restrict__ dyn,
    const float* __restrict__ dist,  const float* __restrict__ W_s,
    const float* __restrict__ b_s,   const float* __restrict__ W_d,
    const float* __restrict__ b_d,   const float* __restrict__ W_i,
    const float* __restrict__ W_h,   const float* __restrict__ b_i,
    const float* __restrict__ b_h,   const float* __restrict__ W_att,
    const float* __restrict__ v_att, const float* __restrict__ W_c,
    const float* __restrict__ b_c,   const int* __restrict__ steps_p,
    float* __restrict__ out) {
  const int b = blockIdx.x;
  const int tid = threadIdx.x;
  const int T = steps_p[0];
  const int lane = tid & 63;
  const int wv = tid >> 6;

  __shared__ __align__(16) float4 xyd[SEQN];     // x, y, dem, -
  __shared__ __align__(16) float4 kbuf[HD];      // paired: B0,B1,A2,v
  __shared__ __align__(16) float4 gpack[NG];     // G0,G1,G2,(b_i+b_h)
  __shared__ __align__(16) float Cp[HD];
  __shared__ __align__(16) float A0a[HD], A1a[HD], D0a[HD];
  __shared__ __align__(16) float C0a[HD], C1a[HD], C2a[HD], bca[HD];
  __shared__ __align__(16) float dba[SEQN], d2d[SEQN];
  __shared__ __align__(16) float hstm[HD], cstm[HD], hlm[HD];
  __shared__ __align__(16) float gates[NG];
  __shared__ __align__(16) float partA[NG], partB[NG];
  __shared__ __align__(16) float wc2v[HD];
  __shared__ __align__(16) float logitA[SEQN];
  __shared__ unsigned maskA[SEQN];
  __shared__ __align__(16) float ws0[HD], ws1[HD], bsv[HD];
  __shared__ __align__(16) float wd0[HD], wd1[HD], wd2[HD], bdv[HD];
  __shared__ float wredv[4]; __shared__ int wredi[4];
  __shared__ float wredm[4], wsum[4], wpx[4], wpy[4], wps[4];
  __shared__ float s_fuel, s_time, s_decx, s_decy, s_mx, s_sum, s_px, s_py, s_ps;
  __shared__ int s_idx, s_old;

  const float* distb = dist + (size_t)b * SEQN * SEQN;

  // ---------------- prologue ----------------
  if (tid < HD) {
    ws0[tid] = W_s[2 * tid]; ws1[tid] = W_s[2 * tid + 1]; bsv[tid] = b_s[tid];
    wd0[tid] = W_d[3 * tid]; wd1[tid] = W_d[3 * tid + 1]; wd2[tid] = W_d[3 * tid + 2];
    bdv[tid] = b_d[tid]; bca[tid] = b_c[tid];
    hstm[tid] = 0.0f; cstm[tid] = 0.0f;
  }
  if (tid < SEQN) {
    int s = tid;
    float xv = statc[b * 2 * SEQN + s];
    float yv = statc[b * 2 * SEQN + SEQN + s];
    float dm = dyn[b * 3 * SEQN + 2 * SEQN + s];
    xyd[s] = make_float4(xv, yv, dm, 0.0f);
    d2d[s] = distb[(size_t)s * SEQN];
    float d10 = distb[1 * SEQN + 0], d20 = distb[2 * SEQN + 0], d30 = distb[3 * SEQN + 0];
    float d1s = distb[1 * SEQN + s], d2s = distb[2 * SEQN + s], d3s = distb[3 * SEQN + s];
    float m = fminf(fminf(__fadd_rn(d10, d1s), __fadd_rn(d20, d2s)), __fadd_rn(d30, d3s));
    dba[s] = (s == 0) ? 0.0f : m;
    maskA[s] = 1u;
  }
  if (tid == 0) {
    s_fuel = dyn[b * 3 * SEQN + 0];
    s_time = dyn[b * 3 * SEQN + SEQN + 0];
    s_old = 0;
  }
  __syncthreads();

  // weight folds (redundant per block; deterministic)
  if (tid < HD) {
    int k = tid;
    const float* row = W_att + (size_t)k * 384;
    float B0 = 0, B1 = 0, B2 = 0, A0 = 0, A1 = 0, A2 = 0, A3 = 0;
    for (int c = 0; c < HD; ++c) {
      float w1 = row[c], w2 = row[128 + c];
      B0 = fmaf(w1, ws0[c], B0); B1 = fmaf(w1, ws1[c], B1); B2 = fmaf(w1, bsv[c], B2);
      A0 = fmaf(w2, wd0[c], A0); A1 = fmaf(w2, wd1[c], A1);
      A2 = fmaf(w2, wd2[c], A2); A3 = fmaf(w2, bdv[c], A3);
    }
    int pk = ((k & 63) << 1) | (k >> 6);
    kbuf[pk] = make_float4(B0, B1, A2, v_att[k]);
    A0a[k] = A0; A1a[k] = A1; D0a[k] = __fadd_rn(B2, A3);
  } else if (tid < 2 * HD) {
    int o = tid - HD;
    const float* row = W_c + (size_t)o * 256;
    float C0 = 0, C1 = 0, C2 = 0;
    for (int c = 0; c < HD; ++c) {
      float w = row[c];
      C0 = fmaf(w, ws0[c], C0); C1 = fmaf(w, ws1[c], C1); C2 = fmaf(w, bsv[c], C2);
    }
    C0a[o] = C0; C1a[o] = C1; C2a[o] = C2;
  }
  {
    int j = tid;
    const float* row = W_i + (size_t)j * HD;
    float g0 = 0, g1 = 0, g2 = 0;
    for (int c = 0; c < HD; ++c) {
      float w = row[c];
      g0 = fmaf(w, ws0[c], g0); g1 = fmaf(w, ws1[c], g1); g2 = fmaf(w, bsv[c], g2);
    }
    gpack[j] = make_float4(g0, g1, g2, __fadd_rn(b_i[j], b_h[j]));
  }
  // register-resident weights
  float whreg[HD];
#pragma unroll
  for (int c = 0; c < HD; ++c) whreg[c] = W_h[(size_t)tid * HD + c];
  const int kq = tid >> 2, qq = tid & 3;
  float wahreg[32], wc2reg[32];
#pragma unroll
  for (int i = 0; i < 32; ++i) {
    wahreg[i] = W_att[(size_t)kq * 384 + 256 + qq * 32 + i];
    wc2reg[i] = W_c[(size_t)kq * 256 + HD + qq * 32 + i];
  }
  if (tid == 0) { float4 p0 = xyd[0]; s_decx = p0.x; s_decy = p0.y; }
  __syncthreads();

  float* out_probs = out;
  float* out_tours = out + (size_t)BSZ * T * SEQN;
  float* out_logps = out_tours + (size_t)BSZ * T;

  // ---------------- decode loop ----------------
  for (int t = 0; t < T; ++t) {
    // P1: gates[j] = (W_i@dec_in fold) + W_h@hst + (b_i+b_h)
    {
      float4 gp = gpack[tid];
      float md = fmaf(gp.x, s_decx, fmaf(gp.y, s_decy, gp.z));
      float mh = 0.0f;
      const float4* h4 = (const float4*)hstm;
#pragma unroll
      for (int c4 = 0; c4 < HD / 4; ++c4) {
        float4 hh = h4[c4];
        mh = fmaf(whreg[4 * c4 + 0], hh.x, mh);
        mh = fmaf(whreg[4 * c4 + 1], hh.y, mh);
        mh = fmaf(whreg[4 * c4 + 2], hh.z, mh);
        mh = fmaf(whreg[4 * c4 + 3], hh.w, mh);
      }
      gates[tid] = __fadd_rn(__fadd_rn(md, mh), gp.w);
    }
    __syncthreads();
    // P2: LSTM pointwise (double-rounded transcendentals)
    if (tid < HD) {
      int c = tid;
      float ig = gates[c], fg = gates[HD + c], gg = gates[2 * HD + c], og = gates[3 * HD + c];
      float sfg = (float)(1.0 / (1.0 + exp(-(double)fg)));
      float sgi = (float)(1.0 / (1.0 + exp(-(double)ig)));
      float tgg = (float)tanh((double)gg);
      float m1 = __fmul_rn(sfg, cstm[c]);
      float m2 = __fmul_rn(sgi, tgg);
      float cn = __fadd_rn(m1, m2);
      float sog = (float)(1.0 / (1.0 + exp(-(double)og)));
      float tcn = (float)tanh((double)cn);
      cstm[c] = cn;
      hlm[c] = __fmul_rn(sog, tcn);
    }
    __syncthreads();
    // P3: partials for W_att_h@h_lstm and W_c[:,128:]@h_lstm
    {
      float pw = 0.0f, pc = 0.0f;
      const float4* hl4 = (const float4*)(hlm + qq * 32);
#pragma unroll
      for (int i4 = 0; i4 < 8; ++i4) {
        float4 hh = hl4[i4];
        pw = fmaf(wahreg[4 * i4 + 0], hh.x, pw); pc = fmaf(wc2reg[4 * i4 + 0], hh.x, pc);
        pw = fmaf(wahreg[4 * i4 + 1], hh.y, pw); pc = fmaf(wc2reg[4 * i4 + 1], hh.y, pc);
        pw = fmaf(wahreg[4 * i4 + 2], hh.z, pw); pc = fmaf(wc2reg[4 * i4 + 2], hh.z, pc);
        pw = fmaf(wahreg[4 * i4 + 3], hh.w, pw); pc = fmaf(wc2reg[4 * i4 + 3], hh.w, pc);
      }
      partA[tid] = pw; partB[tid] = pc;
    }
    __syncthreads();
    // P4: per-step C[k] = D0 + A0*fuel + A1*time + wh[k]; stash wc2v
    if (tid < HD) {
      int k = tid;
      float whk = __fadd_rn(__fadd_rn(__fadd_rn(partA[4 * k], partA[4 * k + 1]), partA[4 * k + 2]), partA[4 * k + 3]);
      wc2v[k]   = __fadd_rn(__fadd_rn(__fadd_rn(partB[4 * k], partB[4 * k + 1]), partB[4 * k + 2]), partB[4 * k + 3]);
      float Ck = fmaf(A0a[k], s_fuel, fmaf(A1a[k], s_time, __fadd_rn(D0a[k], whk)));
      Cp[((k & 63) << 1) | (k >> 6)] = Ck;
    }
    __syncthreads();
    // P5: e[s] partials — thread (s, half) sums 64 k's
    {
      int s = tid >> 1, hf = tid & 1;
      float4 xs = xyd[s];
      float acc = 0.0f;
#pragma unroll 16
      for (int i = 0; i < 64; ++i) {
        int pk = 2 * i + hf;
        float4 kb = kbuf[pk];
        float Tv = fmaf(kb.x, xs.x, fmaf(kb.y, xs.y, fmaf(kb.z, xs.z, Cp[pk])));
        acc = fmaf(kb.w, tanhf(Tv), acc);
      }
      partA[tid] = acc;
    }
    __syncthreads();
    // P6: logits, gumbel, joint argmax(score)/max(logit) reduce
    if (tid < SEQN) {
      int s = tid;
      float ev = __fadd_rn(partA[2 * s], partA[2 * s + 1]);
      float lg = maskA[s] ? ev : NEGV;
      logitA[s] = lg;
      unsigned k0, k1; step_key(t, k0, k1);
      unsigned rb = rand_bits32(k0, k1, b * SEQN + s);
      float f = __uint_as_float((rb >> 9) | 0x3f800000u) - 1.0f;
      float u = fmaxf(TINYF, __fadd_rn(f, TINYF));
      float l1 = (float)log((double)u);
      float l2 = (float)log((double)(-l1));
      float gmb = -l2;
      float sc = __fadd_rn(gmb, lg);
      float av = sc; int ai = s; float mv = lg;
#pragma unroll
      for (int off = 1; off < 64; off <<= 1) {
        float ov = __shfl_xor(av, off, 64);
        int   oi = __shfl_xor(ai, off, 64);
        float om = __shfl_xor(mv, off, 64);
        if (ov > av || (ov == av && oi < ai)) { av = ov; ai = oi; }
        mv = fmaxf(mv, om);
      }
      if (lane == 0) { wredv[wv] = av; wredi[wv] = ai; wredm[wv] = mv; }
    }
    __syncthreads();
    if (tid == 0) {
      float bv = wredv[0]; int bi = wredi[0]; float bm = wredm[0];
      for (int w = 1; w < 4; ++w) {
        if (wredv[w] > bv) { bv = wredv[w]; bi = wredi[w]; }
        bm = fmaxf(bm, wredm[w]);
      }
      s_idx = bi; s_mx = bm;
    }
    __syncthreads();
    // P7: softmax denominator
    float pe = 0.0f;
    if (tid < SEQN) {
      pe = (float)exp((double)__fsub_rn(logitA[tid], s_mx));
      float sm = pe;
#pragma unroll
      for (int off = 1; off < 64; off <<= 1) sm = __fadd_rn(sm, __shfl_xor(sm, off, 64));
      if (lane == 0) wsum[wv] = sm;
    }
    __syncthreads();
    if (tid == 0)
      s_sum = __fadd_rn(__fadd_rn(__fadd_rn(wsum[0], wsum[1]), wsum[2]), wsum[3]);
    __syncthreads();
    // P8: probs out, logp/tour out, context reductions
    if (tid < SEQN) {
      int s = tid;
      float pr = __fdiv_rn(pe, s_sum);
      out_probs[((size_t)b * T + t) * SEQN + s] = pr;
      float4 xs = xyd[s];
      float px = __fmul_rn(pr, xs.x), py = __fmul_rn(pr, xs.y), ps = pr;
#pragma unroll
      for (int off = 1; off < 64; off <<= 1) {
        px = __fadd_rn(px, __shfl_xor(px, off, 64));
        py = __fadd_rn(py, __shfl_xor(py, off, 64));
        ps = __fadd_rn(ps, __shfl_xor(ps, off, 64));
      }
      if (lane == 0) { wpx[wv] = px; wpy[wv] = py; wps[wv] = ps; }
      if (s == s_idx) {
        float lp = __fsub_rn(__fsub_rn(logitA[s], s_mx), (float)log((double)s_sum));
        out_logps[(size_t)b * T + t] = lp;
        out_tours[(size_t)b * T + t] = (float)s;
      }
    }
    __syncthreads();
    if (tid == 0) {
      s_px = __fadd_rn(__fadd_rn(__fadd_rn(wpx[0], wpx[1]), wpx[2]), wpx[3]);
      s_py = __fadd_rn(__fadd_rn(__fadd_rn(wpy[0], wpy[1]), wpy[2]), wpy[3]);
      s_ps = __fadd_rn(__fadd_rn(__fadd_rn(wps[0], wps[1]), wps[2]), wps[3]);
      int ni = s_idx;
      float dis = distb[(size_t)s_old * SEQN + ni];
      float fl = __fsub_rn(s_fuel, __fmul_rn(0.2f, dis));
      float tm = __fsub_rn(s_time, __fdiv_rn(dis, 60.0f));
      if (ni <= 3) fl = 60.0f;   // depot or AFS refuel
      if (ni == 0) tm = 11.0f;   // depot time reset
      s_fuel = fl; s_time = tm;
      if (ni > 3) ((float*)&xyd[ni])[2] = 0.0f;  // demand served
      float4 pn = xyd[ni];
      s_decx = pn.x; s_decy = pn.y;
      s_old = ni;
    }
    __syncthreads();
    // P9: h_new (-> hst) and next-step mask
    if (tid < HD) {
      int o = tid;
      float ctxd = fmaf(C0a[o], s_px, fmaf(C1a[o], s_py, __fmul_rn(C2a[o], s_ps)));
      float val = __fadd_rn(__fadd_rn(ctxd, wc2v[o]), bca[o]);
      hstm[o] = (float)tanh((double)val);
    }
    if (tid < SEQN) {
      int s = tid, ni = s_idx;
      float dn = distb[(size_t)ni * SEQN + s];
      bool fok = s_fuel >= __fmul_rn(0.2f, __fadd_rn(dn, dba[s]));
      bool tok = s_time >= __fdiv_rn(__fadd_rn(dn, d2d[s]), 60.0f);
      bool cust = (xyd[s].z > 0.0f) && fok && tok;
      unsigned mk = (s <= 3) ? (unsigned)(s != ni) : (unsigned)cust;
      if (s == 0) mk = 1u;
      maskA[s] = mk;
    }
    __syncthreads();
  }
}

extern "C" void kernel_launch(void* const* d_in, const int* in_sizes, int n_in,
                              void* d_out, int out_size, void* d_ws, size_t ws_size,
                              hipStream_t stream) {
  (void)in_sizes; (void)n_in; (void)out_size; (void)d_ws; (void)ws_size;
  evrp_kernel<<<dim3(BSZ), dim3(512), 0, stream>>>(
      (const float*)d_in[0],  (const float*)d_in[1],  (const float*)d_in[2],
      (const float*)d_in[3],  (const float*)d_in[4],  (const float*)d_in[5],
      (const float*)d_in[6],  (const float*)d_in[7],  (const float*)d_in[8],
      (const float*)d_in[9],  (const float*)d_in[10], (const float*)d_in[11],
      (const float*)d_in[12], (const float*)d_in[13], (const float*)d_in[14],
      (const int*)d_in[15],   (float*)d_out);
}

// Round 2
// 1358.879 us; speedup vs baseline: 1.8761x; 1.8761x over previous
//
#include <hip/hip_runtime.h>
#include <cmath>

// EVRP solver rollout — one block per batch element, whole 128-step decode
// on-device. PRNG: JAX threefry2x32, partitionable scheme (verified passing).
#define BSZ 256
#define SEQN 256
#define HD 128
#define NG 512
#define NEGV -1000000000.0f
#define TINYF 1.17549435e-38f

static __device__ __forceinline__ void tf2x32(unsigned k0, unsigned k1,
                                              unsigned x0, unsigned x1,
                                              unsigned &o0, unsigned &o1) {
  unsigned ks2 = k0 ^ k1 ^ 0x1BD11BDAu;
#define TFR(r) { x0 += x1; x1 = (x1 << (r)) | (x1 >> (32 - (r))); x1 ^= x0; }
  x0 += k0; x1 += k1;
  TFR(13) TFR(15) TFR(26) TFR(6)
  x0 += k1; x1 += ks2 + 1u;
  TFR(17) TFR(29) TFR(16) TFR(24)
  x0 += ks2; x1 += k0 + 2u;
  TFR(13) TFR(15) TFR(26) TFR(6)
  x0 += k0; x1 += k1 + 3u;
  TFR(17) TFR(29) TFR(16) TFR(24)
  x0 += k1; x1 += ks2 + 4u;
  TFR(13) TFR(15) TFR(26) TFR(6)
  x0 += ks2; x1 += k0 + 5u;
#undef TFR
  o0 = x0; o1 = x1;
}

// tanh(x) = sign(x) * (1 - e^{-2|x|}) / (1 + e^{-2|x|}); ~9 VALU + 1 trans.
static __device__ __forceinline__ float fast_tanh(float x) {
  float y = __fmul_rn(x, 2.885390081777927f);            // x * 2*log2(e)
  float ay = __int_as_float(__float_as_int(y) | 0x80000000u); // -|y|
  float q = __builtin_amdgcn_exp2f(ay);                  // e^{-2|x|}
  float d = __fadd_rn(1.0f, q);
  float n = __fsub_rn(1.0f, q);
  float r = __fmul_rn(n, __builtin_amdgcn_rcpf(d));
  unsigned sgn = (unsigned)__float_as_int(x) & 0x80000000u;
  return __int_as_float(__float_as_int(r) | sgn);
}

__global__ __launch_bounds__(512, 1) void evrp_kernel(
    const float* __restrict__ statc, const float* __restrict__ dyn,
    const float* __restrict__ dist,  const float* __restrict__ W_s,
    const float* __restrict__ b_s,   const float* __restrict__ W_d,
    const float* __restrict__ b_d,   const float* __restrict__ W_i,
    const float* __restrict__ W_h,   const float* __restrict__ b_i,
    const float* __restrict__ b_h,   const float* __restrict__ W_att,
    const float* __restrict__ v_att, const float* __restrict__ W_c,
    const float* __restrict__ b_c,   const int* __restrict__ steps_p,
    float* __restrict__ out) {
  const int b = blockIdx.x;
  const int tid = threadIdx.x;
  const int T = steps_p[0];
  const int lane = tid & 63;
  const int wv = tid >> 6;
  const int s = tid >> 1;      // pair node id
  const int hf = tid & 1;      // pair half
  const int kq = tid >> 2, qq = tid & 3;

  __shared__ __align__(16) float4 gpack[NG];   // G0,G1,G2,(b_i+b_h)
  __shared__ __align__(16) float4 kb4[HD];     // B0,B1,A2,v_att
  __shared__ __align__(16) float Cp[HD];
  __shared__ __align__(16) float A0a[HD], A1a[HD], D0a[HD];
  __shared__ __align__(16) float C0a[HD], C1a[HD], C2a[HD], bca[HD];
  __shared__ __align__(16) float hstm[HD], hlm[HD];
  __shared__ __align__(16) float gates[NG];
  __shared__ __align__(16) float wc2v[HD];
  __shared__ __align__(16) float2 xy2[SEQN];
  __shared__ __align__(16) float drow[SEQN];
  __shared__ __align__(16) float ws0[HD], ws1[HD], bsv[HD];
  __shared__ __align__(16) float wd0[HD], wd1[HD], wd2[HD], bdv[HD];
  __shared__ float rv[8], rS[8], rpx[8], rpy[8];
  __shared__ int ri[8];

  const float* distb = dist + (size_t)b * SEQN * SEQN;

  // ---------------- prologue: loads ----------------
  if (tid < HD) {
    ws0[tid] = W_s[2 * tid]; ws1[tid] = W_s[2 * tid + 1]; bsv[tid] = b_s[tid];
    wd0[tid] = W_d[3 * tid]; wd1[tid] = W_d[3 * tid + 1]; wd2[tid] = W_d[3 * tid + 2];
    bdv[tid] = b_d[tid]; bca[tid] = b_c[tid];
    hstm[tid] = 0.0f;
  }
  // per-pair node state (registers; both lanes hold identical copies)
  float xreg = statc[b * 2 * SEQN + s];
  float yreg = statc[b * 2 * SEQN + SEQN + s];
  float demreg = dyn[b * 3 * SEQN + 2 * SEQN + s];
  float d2dR = distb[(size_t)s * SEQN];
  float dbaR;
  {
    float d10 = distb[1 * SEQN + 0], d20 = distb[2 * SEQN + 0], d30 = distb[3 * SEQN + 0];
    float d1s = distb[1 * SEQN + s], d2s = distb[2 * SEQN + s], d3s = distb[3 * SEQN + s];
    float m = fminf(fminf(__fadd_rn(d10, d1s), __fadd_rn(d20, d2s)), __fadd_rn(d30, d3s));
    dbaR = (s == 0) ? 0.0f : m;
  }
  bool maskR = true;
  if (hf == 0) { xy2[s] = make_float2(xreg, yreg); drow[s] = distb[s]; }
  float fuelR = dyn[b * 3 * SEQN + 0];
  float timeR = dyn[b * 3 * SEQN + SEQN + 0];
  float cstR = 0.0f;                 // LSTM cell state (thread tid<128 owns c=tid)
  __syncthreads();

  // ---------------- prologue: weight folds + register weights ----------------
  if (tid < HD) {
    int k = tid;
    const float* row = W_att + (size_t)k * 384;
    float B0 = 0, B1 = 0, B2 = 0, A0 = 0, A1 = 0, A2 = 0, A3 = 0;
    for (int c = 0; c < HD; ++c) {
      float w1 = row[c], w2 = row[128 + c];
      B0 = fmaf(w1, ws0[c], B0); B1 = fmaf(w1, ws1[c], B1); B2 = fmaf(w1, bsv[c], B2);
      A0 = fmaf(w2, wd0[c], A0); A1 = fmaf(w2, wd1[c], A1);
      A2 = fmaf(w2, wd2[c], A2); A3 = fmaf(w2, bdv[c], A3);
    }
    kb4[k] = make_float4(B0, B1, A2, v_att[k]);
    A0a[k] = A0; A1a[k] = A1; D0a[k] = __fadd_rn(B2, A3);
  } else if (tid < 2 * HD) {
    int o = tid - HD;
    const float* row = W_c + (size_t)o * 256;
    float C0 = 0, C1 = 0, C2 = 0;
    for (int c = 0; c < HD; ++c) {
      float w = row[c];
      C0 = fmaf(w, ws0[c], C0); C1 = fmaf(w, ws1[c], C1); C2 = fmaf(w, bsv[c], C2);
    }
    C0a[o] = C0; C1a[o] = C1; C2a[o] = C2;
  }
  {
    const float* row = W_i + (size_t)tid * HD;
    float g0 = 0, g1 = 0, g2 = 0;
    for (int c = 0; c < HD; ++c) {
      float w = row[c];
      g0 = fmaf(w, ws0[c], g0); g1 = fmaf(w, ws1[c], g1); g2 = fmaf(w, bsv[c], g2);
    }
    gpack[tid] = make_float4(g0, g1, g2, __fadd_rn(b_i[tid], b_h[tid]));
  }
  // register-resident weights (VGPR budget 256 via launch_bounds(512,1))
  float whreg[HD];
#pragma unroll
  for (int c = 0; c < HD; ++c) whreg[c] = W_h[(size_t)tid * HD + c];
  float wahreg[32], wc2reg[32];
#pragma unroll
  for (int i = 0; i < 32; ++i) {
    wahreg[i] = W_att[(size_t)kq * 384 + 256 + qq * 32 + i];
    wc2reg[i] = W_c[(size_t)kq * 256 + HD + qq * 32 + i];
  }
  __syncthreads();

  float decxR = xy2[0].x, decyR = xy2[0].y;

  float* out_probs = out;
  float* out_tours = out + (size_t)BSZ * T * SEQN;
  float* out_logps = out_tours + (size_t)BSZ * T;

  // ---------------- decode loop (6 barriers/step) ----------------
  for (int t = 0; t < T; ++t) {
    // A: gates[j] = fold(W_i@dec_in) + W_h@hst + (b_i+b_h)   [all 512]
    {
      float4 gp = gpack[tid];
      float md = fmaf(gp.x, decxR, fmaf(gp.y, decyR, gp.z));
      float a0 = 0, a1 = 0, a2 = 0, a3 = 0;
      const float4* h4 = (const float4*)hstm;
#pragma unroll
      for (int c4 = 0; c4 < HD / 4; ++c4) {
        float4 hh = h4[c4];
        a0 = fmaf(whreg[4 * c4 + 0], hh.x, a0);
        a1 = fmaf(whreg[4 * c4 + 1], hh.y, a1);
        a2 = fmaf(whreg[4 * c4 + 2], hh.z, a2);
        a3 = fmaf(whreg[4 * c4 + 3], hh.w, a3);
      }
      float mh = __fadd_rn(__fadd_rn(a0, a1), __fadd_rn(a2, a3));
      gates[tid] = __fadd_rn(__fadd_rn(md, mh), gp.w);
    }
    __syncthreads();                                   // b1
    // B: LSTM pointwise (f32 ocml)                     [tid<128]
    if (tid < HD) {
      int c = tid;
      float ig = gates[c], fg = gates[HD + c], gg = gates[2 * HD + c], og = gates[3 * HD + c];
      float sfg = 1.0f / (1.0f + expf(-fg));
      float sgi = 1.0f / (1.0f + expf(-ig));
      float tgg = tanhf(gg);
      float cn = __fadd_rn(__fmul_rn(sfg, cstR), __fmul_rn(sgi, tgg));
      cstR = cn;
      hlm[c] = __fmul_rn(1.0f / (1.0f + expf(-og)), tanhf(cn));
    }
    __syncthreads();                                   // b2
    // C: W_att_h@h and W_c[:,128:]@h partials + quad-shuffle combine [all 512]
    {
      float pw = 0.0f, pc = 0.0f;
      const float4* hl4 = (const float4*)(hlm + qq * 32);
#pragma unroll
      for (int i4 = 0; i4 < 8; ++i4) {
        float4 hh = hl4[i4];
        pw = fmaf(wahreg[4 * i4 + 0], hh.x, pw); pc = fmaf(wc2reg[4 * i4 + 0], hh.x, pc);
        pw = fmaf(wahreg[4 * i4 + 1], hh.y, pw); pc = fmaf(wc2reg[4 * i4 + 1], hh.y, pc);
        pw = fmaf(wahreg[4 * i4 + 2], hh.z, pw); pc = fmaf(wc2reg[4 * i4 + 2], hh.z, pc);
        pw = fmaf(wahreg[4 * i4 + 3], hh.w, pw); pc = fmaf(wc2reg[4 * i4 + 3], hh.w, pc);
      }
      float pw1 = __fadd_rn(pw, __shfl_xor(pw, 1, 64));
      float pc1 = __fadd_rn(pc, __shfl_xor(pc, 1, 64));
      float pw2 = __fadd_rn(pw1, __shfl_xor(pw1, 2, 64));
      float pc2 = __fadd_rn(pc1, __shfl_xor(pc1, 2, 64));
      if (qq == 0) {
        wc2v[kq] = pc2;
        Cp[kq] = fmaf(A0a[kq], fuelR, fmaf(A1a[kq], timeR, __fadd_rn(D0a[kq], pw2)));
      }
    }
    __syncthreads();                                   // b3
    // E: e[s] tanh loop + gumbel + single fused wave reduction [all 512]
    float pe, lg;
    int ni;
    float S, px, py;
    {
      float acc = 0.0f;
      const int base = hf * 64;
#pragma unroll 16
      for (int i = 0; i < 64; ++i) {
        float4 kb = kb4[base + i];
        float Tv = fmaf(kb.x, xreg, fmaf(kb.y, yreg, fmaf(kb.z, demreg, Cp[base + i])));
        acc = fmaf(kb.w, fast_tanh(Tv), acc);
      }
      float e = __fadd_rn(acc, __shfl_xor(acc, 1, 64));   // both lanes identical
      lg = maskR ? e : NEGV;
      unsigned k0, k1, rb, rjunk;
      tf2x32(0u, 1u, 0u, (unsigned)t, k0, k1);            // keys[t]
      tf2x32(k0, k1, 0u, (unsigned)(b * SEQN + s), rb, rjunk);
      {
        unsigned o0 = rb, o1 = rjunk; rb = o0 ^ o1;
      }
      float f = __uint_as_float((rb >> 9) | 0x3f800000u) - 1.0f;
      float u = fmaxf(TINYF, __fadd_rn(f, TINYF));
      float l1 = (float)log((double)u);
      float l2 = (float)log((double)(-l1));
      float gmb = -l2;
      pe = expf(lg);
      float sc = __fadd_rn(gmb, lg);
      float av = sc; int ai = s;
      S = pe; px = __fmul_rn(pe, xreg); py = __fmul_rn(pe, yreg);
#pragma unroll
      for (int off = 2; off < 64; off <<= 1) {
        float ov = __shfl_xor(av, off, 64);
        int   oi = __shfl_xor(ai, off, 64);
        if (ov > av || (ov == av && oi < ai)) { av = ov; ai = oi; }
        S  = __fadd_rn(S,  __shfl_xor(S,  off, 64));
        px = __fadd_rn(px, __shfl_xor(px, off, 64));
        py = __fadd_rn(py, __shfl_xor(py, off, 64));
      }
      if (lane == 0) { rv[wv] = av; ri[wv] = ai; rS[wv] = S; rpx[wv] = px; rpy[wv] = py; }
    }
    __syncthreads();                                   // b4
    // F: redundant final reduce + state update + outputs   [all 512]
    float cx, cy, dn;
    {
      float bv = rv[0]; int bi = ri[0];
#pragma unroll
      for (int w = 1; w < 8; ++w) {
        if (rv[w] > bv) { bv = rv[w]; bi = ri[w]; }
      }
      ni = bi;
      S = rS[0]; px = rpx[0]; py = rpy[0];
#pragma unroll
      for (int w = 1; w < 8; ++w) {
        S = __fadd_rn(S, rS[w]); px = __fadd_rn(px, rpx[w]); py = __fadd_rn(py, rpy[w]);
      }
      // early-issue next distance row (mask + drow), consumed in G
      dn = distb[(size_t)ni * SEQN + s];
      float dis = drow[ni];
      float fl = __fsub_rn(fuelR, __fmul_rn(0.2f, dis));
      float tm = __fsub_rn(timeR, __fdiv_rn(dis, 60.0f));
      if (ni <= 3) fl = 60.0f;
      if (ni == 0) tm = 11.0f;
      fuelR = fl; timeR = tm;
      if (s == ni && ni > 3) demreg = 0.0f;
      float2 dxy = xy2[ni];
      decxR = dxy.x; decyR = dxy.y;
      float pr = __fdiv_rn(pe, S);
      if (hf == 0) out_probs[((size_t)b * T + t) * SEQN + s] = pr;
      if (s == ni && hf == 0) {
        out_tours[(size_t)b * T + t] = (float)ni;
        out_logps[(size_t)b * T + t] = __fsub_rn(lg, (float)log((double)S));
      }
      cx = __fdiv_rn(px, S); cy = __fdiv_rn(py, S);
    }
    __syncthreads();                                   // b5 (drow reads done)
    // G: h_new + next mask + drow rotate                  [all 512]
    if (tid < HD) {
      int o = tid;
      float ctxd = fmaf(C0a[o], cx, fmaf(C1a[o], cy, C2a[o]));
      float val = __fadd_rn(__fadd_rn(ctxd, wc2v[o]), bca[o]);
      hstm[o] = tanhf(val);
    }
    {
      bool fok = fuelR >= __fmul_rn(0.2f, __fadd_rn(dn, dbaR));
      bool tok = timeR >= __fdiv_rn(__fadd_rn(dn, d2dR), 60.0f);
      bool cust = (demreg > 0.0f) && fok && tok;
      maskR = (s <= 3) ? (s != ni) : cust;
      if (s == 0) maskR = true;
      if (hf == 0) drow[s] = dn;
    }
    __syncthreads();                                   // b6
  }
}

extern "C" void kernel_launch(void* const* d_in, const int* in_sizes, int n_in,
                              void* d_out, int out_size, void* d_ws, size_t ws_size,
                              hipStream_t stream) {
  (void)in_sizes; (void)n_in; (void)out_size; (void)d_ws; (void)ws_size;
  evrp_kernel<<<dim3(BSZ), dim3(512), 0, stream>>>(
      (const float*)d_in[0],  (const float*)d_in[1],  (const float*)d_in[2],
      (const float*)d_in[3],  (const float*)d_in[4],  (const float*)d_in[5],
      (const float*)d_in[6],  (const float*)d_in[7],  (const float*)d_in[8],
      (const float*)d_in[9],  (const float*)d_in[10], (const float*)d_in[11],
      (const float*)d_in[12], (const float*)d_in[13], (const float*)d_in[14],
      (const int*)d_in[15],   (float*)d_out);
}

// Round 3
// 1082.526 us; speedup vs baseline: 2.3550x; 1.2553x over previous
//
#include <hip/hip_runtime.h>
#include <cmath>

// EVRP solver rollout — one block per batch element, 128-step decode on-device.
// PRNG: JAX threefry2x32 partitionable scheme (verified). Discrete state path
// (fuel/time/demand/mask) is bit-exact vs jnp f32; logit path is analog.
#define BSZ 256
#define SEQN 256
#define HD 128
#define NEGV -1000000000.0f
#define TINYF 1.17549435e-38f
#define LOG2E 1.4426950408889634f

static __device__ __forceinline__ void tf2x32(unsigned k0, unsigned k1,
                                              unsigned x0, unsigned x1,
                                              unsigned &o0, unsigned &o1) {
  unsigned ks2 = k0 ^ k1 ^ 0x1BD11BDAu;
#define TFR(r) { x0 += x1; x1 = (x1 << (r)) | (x1 >> (32 - (r))); x1 ^= x0; }
  x0 += k0; x1 += k1;
  TFR(13) TFR(15) TFR(26) TFR(6)
  x0 += k1; x1 += ks2 + 1u;
  TFR(17) TFR(29) TFR(16) TFR(24)
  x0 += ks2; x1 += k0 + 2u;
  TFR(13) TFR(15) TFR(26) TFR(6)
  x0 += k0; x1 += k1 + 3u;
  TFR(17) TFR(29) TFR(16) TFR(24)
  x0 += k1; x1 += ks2 + 4u;
  TFR(13) TFR(15) TFR(26) TFR(6)
  x0 += ks2; x1 += k0 + 5u;
#undef TFR
  o0 = x0; o1 = x1;
}

static __device__ __forceinline__ float fast_tanh(float x) {
  float y = __fmul_rn(x, 2.885390081777927f);                 // 2*log2(e)*x
  float ay = __int_as_float(__float_as_int(y) | 0x80000000u); // -|y|
  float q = __builtin_amdgcn_exp2f(ay);
  float r = __fmul_rn(__fsub_rn(1.0f, q),
                      __builtin_amdgcn_rcpf(__fadd_rn(1.0f, q)));
  unsigned sgn = (unsigned)__float_as_int(x) & 0x80000000u;
  return __int_as_float(__float_as_int(r) | sgn);
}

static __device__ __forceinline__ float fast_sig(float x) {
  float q = __builtin_amdgcn_exp2f(__fmul_rn(x, -LOG2E));
  return __builtin_amdgcn_rcpf(__fadd_rn(1.0f, q));
}

__global__ __attribute__((amdgpu_flat_work_group_size(512, 512)))
__attribute__((amdgpu_waves_per_eu(2, 2)))
void evrp_kernel(
    const float* __restrict__ statc, const float* __restrict__ dyn,
    const float* __restrict__ dist,  const float* __restrict__ W_s,
    const float* __restrict__ b_s,   const float* __restrict__ W_d,
    const float* __restrict__ b_d,   const float* __restrict__ W_i,
    const float* __restrict__ W_h,   const float* __restrict__ b_i,
    const float* __restrict__ b_h,   const float* __restrict__ W_att,
    const float* __restrict__ v_att, const float* __restrict__ W_c,
    const float* __restrict__ b_c,   const int* __restrict__ steps_p,
    float* __restrict__ out) {
  const int b = blockIdx.x;
  const int tid = threadIdx.x;
  const int T = steps_p[0];
  const int lane = tid & 63;
  const int wv = tid >> 6;
  const int s = tid >> 1, hf = tid & 1;      // E/FG mapping
  const int cq = tid >> 2, g = tid & 3;      // AB/C mapping

  __shared__ __align__(16) float4 kbi[HD];    // {B0,B1,A2,C_t} slot 2*(k&63)+(k>>6)
  __shared__ __align__(16) float  v4f[HD];    // v_att packed float4-readable
  __shared__ __align__(16) float  hstm[HD], hlm[HD], wc2v[HD];
  __shared__ __align__(16) float  A0a[HD], A1a[HD], D0a[HD];
  __shared__ __align__(16) float  C0a[HD], C1a[HD], C2a[HD], bca[HD];
  __shared__ __align__(16) float2 xy2[SEQN];
  __shared__ __align__(16) float  drowX[SEQN];
  __shared__ __align__(16) unsigned kAs[256], kBs[256];
  __shared__ __align__(16) float ws0[HD], ws1[HD], bsv[HD];
  __shared__ __align__(16) float wd0[HD], wd1[HD], wd2[HD], bdv[HD];
  __shared__ float rv[8], rS[8], rpx[8], rpy[8];
  __shared__ int ri[8];

  const float* distb = dist + (size_t)b * SEQN * SEQN;

  // ---------------- prologue: loads ----------------
  if (tid < HD) {
    ws0[tid] = W_s[2 * tid]; ws1[tid] = W_s[2 * tid + 1]; bsv[tid] = b_s[tid];
    wd0[tid] = W_d[3 * tid]; wd1[tid] = W_d[3 * tid + 1]; wd2[tid] = W_d[3 * tid + 2];
    bdv[tid] = b_d[tid]; bca[tid] = b_c[tid];
    hstm[tid] = 0.0f;
  }
  float xreg = statc[b * 2 * SEQN + s];
  float yreg = statc[b * 2 * SEQN + SEQN + s];
  float demreg = dyn[b * 3 * SEQN + 2 * SEQN + s];
  float d2dR = distb[(size_t)s * SEQN];
  float dbaR;
  {
    float d10 = distb[1 * SEQN + 0], d20 = distb[2 * SEQN + 0], d30 = distb[3 * SEQN + 0];
    float d1s = distb[1 * SEQN + s], d2s = distb[2 * SEQN + s], d3s = distb[3 * SEQN + s];
    float m = fminf(fminf(__fadd_rn(d10, d1s), __fadd_rn(d20, d2s)), __fadd_rn(d30, d3s));
    dbaR = (s == 0) ? 0.0f : m;
  }
  float dnextR = distb[s];       // row 0 — fills drowX at E_0
  if (hf == 0) xy2[s] = make_float2(xreg, yreg);
  float fuelR = dyn[b * 3 * SEQN + 0];
  float timeR = dyn[b * 3 * SEQN + SEQN + 0];
  float cstR = 0.0f;
  int niR = 0;
  for (int tt = tid; tt < 256; tt += 512) {
    unsigned a0, a1; tf2x32(0u, 1u, 0u, (unsigned)tt, a0, a1);
    kAs[tt] = a0; kBs[tt] = a1;
  }
  __syncthreads();

  // ---------------- prologue: folds + register weights ----------------
  if (tid < HD) {
    int k = tid;
    const float* row = W_att + (size_t)k * 384;
    float B0 = 0, B1 = 0, B2 = 0, A0 = 0, A1 = 0, A2 = 0, A3 = 0;
    for (int c = 0; c < HD; ++c) {
      float w1 = row[c], w2 = row[128 + c];
      B0 = fmaf(w1, ws0[c], B0); B1 = fmaf(w1, ws1[c], B1); B2 = fmaf(w1, bsv[c], B2);
      A0 = fmaf(w2, wd0[c], A0); A1 = fmaf(w2, wd1[c], A1);
      A2 = fmaf(w2, wd2[c], A2); A3 = fmaf(w2, bdv[c], A3);
    }
    kbi[2 * (k & 63) + (k >> 6)] = make_float4(B0, B1, A2, 0.0f);
    A0a[k] = A0; A1a[k] = A1; D0a[k] = __fadd_rn(B2, A3);
    v4f[(2 * ((k & 63) >> 2) + (k >> 6)) * 4 + (k & 3)] = v_att[k];
  } else if (tid < 2 * HD) {
    int o = tid - HD;
    const float* row = W_c + (size_t)o * 256;
    float C0 = 0, C1 = 0, C2 = 0;
    for (int c = 0; c < HD; ++c) {
      float w = row[c];
      C0 = fmaf(w, ws0[c], C0); C1 = fmaf(w, ws1[c], C1); C2 = fmaf(w, bsv[c], C2);
    }
    C0a[o] = C0; C1a[o] = C1; C2a[o] = C2;
  }
  float gp0 = 0, gp1 = 0, gp2 = 0, gpw;
  {
    int j = g * HD + cq;
    const float* row = W_i + (size_t)j * HD;
    for (int c = 0; c < HD; ++c) {
      float w = row[c];
      gp0 = fmaf(w, ws0[c], gp0); gp1 = fmaf(w, ws1[c], gp1); gp2 = fmaf(w, bsv[c], gp2);
    }
    gpw = __fadd_rn(b_i[j], b_h[j]);
  }
  float whreg[HD];
  {
    int j = g * HD + cq;
#pragma unroll
    for (int c = 0; c < HD; ++c) whreg[c] = W_h[(size_t)j * HD + c];
  }
  float wah[32], wc2[32];
#pragma unroll
  for (int i = 0; i < 32; ++i) {
    wah[i] = W_att[(size_t)cq * 384 + 256 + g * 32 + i];
    wc2[i] = W_c[(size_t)cq * 256 + HD + g * 32 + i];
  }
  __syncthreads();

  float decxR = xy2[0].x, decyR = xy2[0].y;

  float* out_probs = out;
  float* out_tours = out + (size_t)BSZ * T * SEQN;
  float* out_logps = out_tours + (size_t)BSZ * T;

  // ---------------- decode loop (4 barriers/step) ----------------
  for (int t = 0; t < T; ++t) {
    // ---- AB: gates + LSTM via quad shuffle ---- [all 512; (cq,g)]
    {
      float m0 = 0, m1 = 0, m2 = 0, m3 = 0;
      const float4* h4 = (const float4*)hstm;
#pragma unroll
      for (int c4 = 0; c4 < HD / 4; ++c4) {
        float4 hh = h4[c4];
        m0 = fmaf(whreg[4 * c4 + 0], hh.x, m0);
        m1 = fmaf(whreg[4 * c4 + 1], hh.y, m1);
        m2 = fmaf(whreg[4 * c4 + 2], hh.z, m2);
        m3 = fmaf(whreg[4 * c4 + 3], hh.w, m3);
      }
      float md = fmaf(gp0, decxR, fmaf(gp1, decyR, gp2));
      float V = __fadd_rn(__fadd_rn(md, __fadd_rn(__fadd_rn(m0, m1), __fadd_rn(m2, m3))), gpw);
      float sg = fast_sig(V), th = fast_tanh(V);
      float q = (g == 2) ? th : sg;
      float u1 = __shfl_xor(q, 1, 64);
      float u2 = __shfl_xor(q, 2, 64);
      float u3 = __shfl_xor(q, 3, 64);
      float qi = (g == 0) ? q  : (g == 1) ? u1 : (g == 2) ? u2 : u3;
      float qf = (g == 0) ? u1 : (g == 1) ? q  : (g == 2) ? u3 : u2;
      float qg = (g == 0) ? u2 : (g == 1) ? u3 : (g == 2) ? q  : u1;
      float qo = (g == 0) ? u3 : (g == 1) ? u2 : (g == 2) ? u1 : q;
      float cn = __fadd_rn(__fmul_rn(qf, cstR), __fmul_rn(qi, qg));
      cstR = cn;
      float hv = __fmul_rn(qo, fast_tanh(cn));
      if (g == 0) hlm[(cq & 96) | ((cq & 31) ^ ((cq >> 5) << 3))] = hv;
    }
    __syncthreads();                               // b1
    // ---- C: W_att_h@h, W_c2@h; write Ck into kbi.w ---- [all 512; (cq,g)]
    {
      float pw = 0.0f, pc = 0.0f;
      const float4* hl4 = (const float4*)hlm;
#pragma unroll
      for (int l4 = 0; l4 < 8; ++l4) {
        float4 hh = hl4[(g << 3) + (l4 ^ (g << 1))];   // XOR-swizzled, conflict-free
        pw = fmaf(wah[l4 * 4 + 0], hh.x, pw); pc = fmaf(wc2[l4 * 4 + 0], hh.x, pc);
        pw = fmaf(wah[l4 * 4 + 1], hh.y, pw); pc = fmaf(wc2[l4 * 4 + 1], hh.y, pc);
        pw = fmaf(wah[l4 * 4 + 2], hh.z, pw); pc = fmaf(wc2[l4 * 4 + 2], hh.z, pc);
        pw = fmaf(wah[l4 * 4 + 3], hh.w, pw); pc = fmaf(wc2[l4 * 4 + 3], hh.w, pc);
      }
      pw = __fadd_rn(pw, __shfl_xor(pw, 1, 64));
      pc = __fadd_rn(pc, __shfl_xor(pc, 1, 64));
      pw = __fadd_rn(pw, __shfl_xor(pw, 2, 64));
      pc = __fadd_rn(pc, __shfl_xor(pc, 2, 64));
      if (g == 0) {
        wc2v[cq] = pc;
        float Ck = fmaf(A0a[cq], fuelR, fmaf(A1a[cq], timeR, __fadd_rn(D0a[cq], pw)));
        kbi[2 * (cq & 63) + (cq >> 6)].w = Ck;
      }
    }
    __syncthreads();                               // b2
    // ---- E: mask, drow fill, tanh loop, gumbel, fused reduce ---- [(s,hf)]
    float pe, lg;
    if (hf == 0) drowX[s] = dnextR;   // row of node niR (prev step's pick)
    bool mk;
    if (t == 0) mk = true;
    else {
      bool fok = fuelR >= __fmul_rn(0.2f, __fadd_rn(dnextR, dbaR));
      bool tok = timeR >= __fdiv_rn(__fadd_rn(dnextR, d2dR), 60.0f);
      bool cust = (demreg > 0.0f) && fok && tok;
      mk = (s <= 3) ? (s != niR) : cust;
      if (s == 0) mk = true;
    }
    {
      unsigned rb;
      { unsigned o0, o1; tf2x32(kAs[t], kBs[t], 0u, (unsigned)(b * SEQN + s), o0, o1); rb = o0 ^ o1; }
      float f = __uint_as_float((rb >> 9) | 0x3f800000u) - 1.0f;
      float u = fmaxf(TINYF, __fadd_rn(f, TINYF));
      float gmb = -logf(-logf(u));
      float acc = 0.0f;
      const float4* v4p = (const float4*)v4f;
#pragma unroll 4
      for (int j = 0; j < 16; ++j) {
        float4 vv = v4p[2 * j + hf];
        float4 kb;
        float Tv;
        kb = kbi[8 * j + 0 + hf];
        Tv = fmaf(kb.x, xreg, fmaf(kb.y, yreg, fmaf(kb.z, demreg, kb.w)));
        acc = fmaf(vv.x, fast_tanh(Tv), acc);
        kb = kbi[8 * j + 2 + hf];
        Tv = fmaf(kb.x, xreg, fmaf(kb.y, yreg, fmaf(kb.z, demreg, kb.w)));
        acc = fmaf(vv.y, fast_tanh(Tv), acc);
        kb = kbi[8 * j + 4 + hf];
        Tv = fmaf(kb.x, xreg, fmaf(kb.y, yreg, fmaf(kb.z, demreg, kb.w)));
        acc = fmaf(vv.z, fast_tanh(Tv), acc);
        kb = kbi[8 * j + 6 + hf];
        Tv = fmaf(kb.x, xreg, fmaf(kb.y, yreg, fmaf(kb.z, demreg, kb.w)));
        acc = fmaf(vv.w, fast_tanh(Tv), acc);
      }
      float e = __fadd_rn(acc, __shfl_xor(acc, 1, 64));
      lg = mk ? e : NEGV;
      pe = __builtin_amdgcn_exp2f(__fmul_rn(lg, LOG2E));
      float sc = __fadd_rn(gmb, lg);
      float av = sc; int ai = s;
      float S = pe, px = __fmul_rn(pe, xreg), py = __fmul_rn(pe, yreg);
#pragma unroll
      for (int off = 2; off < 64; off <<= 1) {
        float ov = __shfl_xor(av, off, 64);
        int   oi = __shfl_xor(ai, off, 64);
        if (ov > av || (ov == av && oi < ai)) { av = ov; ai = oi; }
        S  = __fadd_rn(S,  __shfl_xor(S,  off, 64));
        px = __fadd_rn(px, __shfl_xor(px, off, 64));
        py = __fadd_rn(py, __shfl_xor(py, off, 64));
      }
      if (lane == 0) { rv[wv] = av; ri[wv] = ai; rS[wv] = S; rpx[wv] = px; rpy[wv] = py; }
    }
    __syncthreads();                               // b3
    // ---- FG: final combine, state update, outputs, h_new, drow prefetch ----
    {
      float bv = rv[0]; int bi = ri[0];
#pragma unroll
      for (int w = 1; w < 8; ++w)
        if (rv[w] > bv) { bv = rv[w]; bi = ri[w]; }
      int ni = bi;
      dnextR = distb[(size_t)ni * SEQN + s];       // issued now, consumed next E
      float S = rS[0], px = rpx[0], py = rpy[0];
#pragma unroll
      for (int w = 1; w < 8; ++w) {
        S = __fadd_rn(S, rS[w]); px = __fadd_rn(px, rpx[w]); py = __fadd_rn(py, rpy[w]);
      }
      float dis = drowX[ni];
      float fl = __fsub_rn(fuelR, __fmul_rn(0.2f, dis));
      float tm = __fsub_rn(timeR, __fdiv_rn(dis, 60.0f));
      if (ni <= 3) fl = 60.0f;
      if (ni == 0) tm = 11.0f;
      fuelR = fl; timeR = tm;
      if (s == ni && ni > 3) demreg = 0.0f;
      float2 dxy = xy2[ni];
      decxR = dxy.x; decyR = dxy.y;
      float pr = __fdiv_rn(pe, S);
      if (hf == 0) out_probs[((size_t)b * T + t) * SEQN + s] = pr;
      if (s == ni && hf == 0) {
        out_tours[(size_t)b * T + t] = (float)ni;
        out_logps[(size_t)b * T + t] = __fsub_rn(lg, logf(S));
      }
      if (tid < HD) {
        float cx = __fdiv_rn(px, S), cy = __fdiv_rn(py, S);
        float ctxd = fmaf(C0a[tid], cx, fmaf(C1a[tid], cy, C2a[tid]));
        float val = __fadd_rn(__fadd_rn(ctxd, wc2v[tid]), bca[tid]);
        hstm[tid] = fast_tanh(val);
      }
      niR = ni;
    }
    __syncthreads();                               // b4
  }
}

extern "C" void kernel_launch(void* const* d_in, const int* in_sizes, int n_in,
                              void* d_out, int out_size, void* d_ws, size_t ws_size,
                              hipStream_t stream) {
  (void)in_sizes; (void)n_in; (void)out_size; (void)d_ws; (void)ws_size;
  evrp_kernel<<<dim3(BSZ), dim3(512), 0, stream>>>(
      (const float*)d_in[0],  (const float*)d_in[1],  (const float*)d_in[2],
      (const float*)d_in[3],  (const float*)d_in[4],  (const float*)d_in[5],
      (const float*)d_in[6],  (const float*)d_in[7],  (const float*)d_in[8],
      (const float*)d_in[9],  (const float*)d_in[10], (const float*)d_in[11],
      (const float*)d_in[12], (const float*)d_in[13], (const float*)d_in[14],
      (const int*)d_in[15],   (float*)d_out);
}

// Round 4
// 1011.540 us; speedup vs baseline: 2.5203x; 1.0702x over previous
//
#include <hip/hip_runtime.h>
#include <cmath>

// EVRP solver rollout — one block per batch element, 128-step decode on-device.
// PRNG: JAX threefry2x32 partitionable scheme (verified). Discrete state path
// (fuel/time/demand/mask) is bit-exact vs jnp f32; logit path is analog.
#define BSZ 256
#define SEQN 256
#define HD 128
#define NEGV -1000000000.0f
#define TINYF 1.17549435e-38f
#define LOG2E 1.4426950408889634f

static __device__ __forceinline__ void tf2x32(unsigned k0, unsigned k1,
                                              unsigned x0, unsigned x1,
                                              unsigned &o0, unsigned &o1) {
  unsigned ks2 = k0 ^ k1 ^ 0x1BD11BDAu;
#define TFR(r) { x0 += x1; x1 = (x1 << (r)) | (x1 >> (32 - (r))); x1 ^= x0; }
  x0 += k0; x1 += k1;
  TFR(13) TFR(15) TFR(26) TFR(6)
  x0 += k1; x1 += ks2 + 1u;
  TFR(17) TFR(29) TFR(16) TFR(24)
  x0 += ks2; x1 += k0 + 2u;
  TFR(13) TFR(15) TFR(26) TFR(6)
  x0 += k0; x1 += k1 + 3u;
  TFR(17) TFR(29) TFR(16) TFR(24)
  x0 += k1; x1 += ks2 + 4u;
  TFR(13) TFR(15) TFR(26) TFR(6)
  x0 += ks2; x1 += k0 + 5u;
#undef TFR
  o0 = x0; o1 = x1;
}

static __device__ __forceinline__ float fast_tanh(float x) {
  float y = __fmul_rn(x, 2.885390081777927f);                 // 2*log2(e)*x
  float ay = __int_as_float(__float_as_int(y) | 0x80000000u); // -|y|
  float q = __builtin_amdgcn_exp2f(ay);
  float r = __fmul_rn(__fsub_rn(1.0f, q),
                      __builtin_amdgcn_rcpf(__fadd_rn(1.0f, q)));
  unsigned sgn = (unsigned)__float_as_int(x) & 0x80000000u;
  return __int_as_float(__float_as_int(r) | sgn);
}

static __device__ __forceinline__ float fast_sig(float x) {
  float q = __builtin_amdgcn_exp2f(__fmul_rn(x, -LOG2E));
  return __builtin_amdgcn_rcpf(__fadd_rn(1.0f, q));
}

__global__ __launch_bounds__(512, 2) void evrp_kernel(
    const float* __restrict__ statc, const float* __restrict__ dyn,
    const float* __restrict__ dist,  const float* __restrict__ W_s,
    const float* __restrict__ b_s,   const float* __restrict__ W_d,
    const float* __restrict__ b_d,   const float* __restrict__ W_i,
    const float* __restrict__ W_h,   const float* __restrict__ b_i,
    const float* __restrict__ b_h,   const float* __restrict__ W_att,
    const float* __restrict__ v_att, const float* __restrict__ W_c,
    const float* __restrict__ b_c,   const int* __restrict__ steps_p,
    float* __restrict__ out) {
  const int b = blockIdx.x;
  const int tid = threadIdx.x;
  const int T = steps_p[0];
  const int lane = tid & 63;
  const int wv = tid >> 6;
  const int s = tid >> 1, hf = tid & 1;      // E/FG mapping
  const int cq = tid >> 2, g = tid & 3;      // AB/C mapping

  __shared__ __align__(16) float4 kbi[HD];    // {B0,B1,A2,C_t} slot 2*(k&63)+(k>>6)
  __shared__ __align__(16) float  v4f[HD];    // v_att packed float4-readable
  __shared__ __align__(16) float  hstm[HD], hlm[HD], wc2v[HD];
  __shared__ __align__(16) float  A0a[HD], A1a[HD], D0a[HD];
  __shared__ __align__(16) float  C0a[HD], C1a[HD], C2a[HD], bca[HD];
  __shared__ __align__(16) float2 xy2[SEQN];
  __shared__ __align__(16) float  drowX[SEQN];
  __shared__ __align__(16) unsigned kAs[256], kBs[256];
  __shared__ __align__(16) float ws0[HD], ws1[HD], bsv[HD];
  __shared__ __align__(16) float wd0[HD], wd1[HD], wd2[HD], bdv[HD];
  __shared__ float rv[8], rS[8], rpx[8], rpy[8];
  __shared__ int ri[8];

  const float* distb = dist + (size_t)b * SEQN * SEQN;

  // ---------------- prologue: loads ----------------
  if (tid < HD) {
    ws0[tid] = W_s[2 * tid]; ws1[tid] = W_s[2 * tid + 1]; bsv[tid] = b_s[tid];
    wd0[tid] = W_d[3 * tid]; wd1[tid] = W_d[3 * tid + 1]; wd2[tid] = W_d[3 * tid + 2];
    bdv[tid] = b_d[tid]; bca[tid] = b_c[tid];
    hstm[tid] = 0.0f;
  }
  float xreg = statc[b * 2 * SEQN + s];
  float yreg = statc[b * 2 * SEQN + SEQN + s];
  float demreg = dyn[b * 3 * SEQN + 2 * SEQN + s];
  float d2dR = distb[(size_t)s * SEQN];
  float dbaR;
  {
    float d10 = distb[1 * SEQN + 0], d20 = distb[2 * SEQN + 0], d30 = distb[3 * SEQN + 0];
    float d1s = distb[1 * SEQN + s], d2s = distb[2 * SEQN + s], d3s = distb[3 * SEQN + s];
    float m = fminf(fminf(__fadd_rn(d10, d1s), __fadd_rn(d20, d2s)), __fadd_rn(d30, d3s));
    dbaR = (s == 0) ? 0.0f : m;
  }
  float dnextR = distb[s];       // row 0 — fills drowX at E_0
  if (hf == 0) xy2[s] = make_float2(xreg, yreg);
  float fuelR = dyn[b * 3 * SEQN + 0];
  float timeR = dyn[b * 3 * SEQN + SEQN + 0];
  float cstR = 0.0f;
  int niR = 0;
  for (int tt = tid; tt < 256; tt += 512) {
    unsigned a0, a1; tf2x32(0u, 1u, 0u, (unsigned)tt, a0, a1);
    kAs[tt] = a0; kBs[tt] = a1;
  }
  __syncthreads();

  // ---------------- prologue: folds + register weights ----------------
  if (tid < HD) {
    int k = tid;
    const float* row = W_att + (size_t)k * 384;
    float B0 = 0, B1 = 0, B2 = 0, A0 = 0, A1 = 0, A2 = 0, A3 = 0;
    for (int c = 0; c < HD; ++c) {
      float w1 = row[c], w2 = row[128 + c];
      B0 = fmaf(w1, ws0[c], B0); B1 = fmaf(w1, ws1[c], B1); B2 = fmaf(w1, bsv[c], B2);
      A0 = fmaf(w2, wd0[c], A0); A1 = fmaf(w2, wd1[c], A1);
      A2 = fmaf(w2, wd2[c], A2); A3 = fmaf(w2, bdv[c], A3);
    }
    kbi[2 * (k & 63) + (k >> 6)] = make_float4(B0, B1, A2, 0.0f);
    A0a[k] = A0; A1a[k] = A1; D0a[k] = __fadd_rn(B2, A3);
    v4f[(2 * ((k & 63) >> 2) + (k >> 6)) * 4 + (k & 3)] = v_att[k];
  } else if (tid < 2 * HD) {
    int o = tid - HD;
    const float* row = W_c + (size_t)o * 256;
    float C0 = 0, C1 = 0, C2 = 0;
    for (int c = 0; c < HD; ++c) {
      float w = row[c];
      C0 = fmaf(w, ws0[c], C0); C1 = fmaf(w, ws1[c], C1); C2 = fmaf(w, bsv[c], C2);
    }
    C0a[o] = C0; C1a[o] = C1; C2a[o] = C2;
  }
  float gp0 = 0, gp1 = 0, gp2 = 0, gpw;
  {
    int j = g * HD + cq;
    const float* row = W_i + (size_t)j * HD;
    for (int c = 0; c < HD; ++c) {
      float w = row[c];
      gp0 = fmaf(w, ws0[c], gp0); gp1 = fmaf(w, ws1[c], gp1); gp2 = fmaf(w, bsv[c], gp2);
    }
    gpw = __fadd_rn(b_i[j], b_h[j]);
  }
  // register-resident weights — loaded once, then made OPAQUE so the
  // allocator cannot rematerialize/stream them from memory each step.
  float whreg[HD];
  {
    int j = g * HD + cq;
#pragma unroll
    for (int c = 0; c < HD; ++c) whreg[c] = W_h[(size_t)j * HD + c];
  }
  float wah[32], wc2[32];
#pragma unroll
  for (int i = 0; i < 32; ++i) {
    wah[i] = W_att[(size_t)cq * 384 + 256 + g * 32 + i];
    wc2[i] = W_c[(size_t)cq * 256 + HD + g * 32 + i];
  }
#pragma unroll
  for (int c = 0; c < HD; c += 4)
    asm volatile("" : "+v"(whreg[c]), "+v"(whreg[c + 1]),
                      "+v"(whreg[c + 2]), "+v"(whreg[c + 3]));
#pragma unroll
  for (int i = 0; i < 32; i += 4)
    asm volatile("" : "+v"(wah[i]), "+v"(wah[i + 1]),
                      "+v"(wah[i + 2]), "+v"(wah[i + 3]));
#pragma unroll
  for (int i = 0; i < 32; i += 4)
    asm volatile("" : "+v"(wc2[i]), "+v"(wc2[i + 1]),
                      "+v"(wc2[i + 2]), "+v"(wc2[i + 3]));
  __syncthreads();

  float decxR = xy2[0].x, decyR = xy2[0].y;

  float* out_probs = out;
  float* out_tours = out + (size_t)BSZ * T * SEQN;
  float* out_logps = out_tours + (size_t)BSZ * T;

  // ---------------- decode loop (4 barriers/step) ----------------
  for (int t = 0; t < T; ++t) {
    // ---- AB: gates + LSTM via quad shuffle ---- [all 512; (cq,g)]
    {
      float m0 = 0, m1 = 0, m2 = 0, m3 = 0;
      const float4* h4 = (const float4*)hstm;
#pragma unroll
      for (int c4 = 0; c4 < HD / 4; ++c4) {
        float4 hh = h4[c4];
        m0 = fmaf(whreg[4 * c4 + 0], hh.x, m0);
        m1 = fmaf(whreg[4 * c4 + 1], hh.y, m1);
        m2 = fmaf(whreg[4 * c4 + 2], hh.z, m2);
        m3 = fmaf(whreg[4 * c4 + 3], hh.w, m3);
      }
      float md = fmaf(gp0, decxR, fmaf(gp1, decyR, gp2));
      float V = __fadd_rn(__fadd_rn(md, __fadd_rn(__fadd_rn(m0, m1), __fadd_rn(m2, m3))), gpw);
      float sg = fast_sig(V), th = fast_tanh(V);
      float q = (g == 2) ? th : sg;
      float u1 = __shfl_xor(q, 1, 64);
      float u2 = __shfl_xor(q, 2, 64);
      float u3 = __shfl_xor(q, 3, 64);
      float qi = (g == 0) ? q  : (g == 1) ? u1 : (g == 2) ? u2 : u3;
      float qf = (g == 0) ? u1 : (g == 1) ? q  : (g == 2) ? u3 : u2;
      float qg = (g == 0) ? u2 : (g == 1) ? u3 : (g == 2) ? q  : u1;
      float qo = (g == 0) ? u3 : (g == 1) ? u2 : (g == 2) ? u1 : q;
      float cn = __fadd_rn(__fmul_rn(qf, cstR), __fmul_rn(qi, qg));
      cstR = cn;
      float hv = __fmul_rn(qo, fast_tanh(cn));
      if (g == 0) hlm[(cq & 96) | ((cq & 31) ^ ((cq >> 5) << 3))] = hv;
    }
    __syncthreads();                               // b1
    // ---- C: W_att_h@h, W_c2@h; write Ck into kbi.w ---- [all 512; (cq,g)]
    {
      float pw = 0.0f, pc = 0.0f;
      const float4* hl4 = (const float4*)hlm;
#pragma unroll
      for (int l4 = 0; l4 < 8; ++l4) {
        float4 hh = hl4[(g << 3) + (l4 ^ (g << 1))];   // XOR-swizzled, conflict-free
        pw = fmaf(wah[l4 * 4 + 0], hh.x, pw); pc = fmaf(wc2[l4 * 4 + 0], hh.x, pc);
        pw = fmaf(wah[l4 * 4 + 1], hh.y, pw); pc = fmaf(wc2[l4 * 4 + 1], hh.y, pc);
        pw = fmaf(wah[l4 * 4 + 2], hh.z, pw); pc = fmaf(wc2[l4 * 4 + 2], hh.z, pc);
        pw = fmaf(wah[l4 * 4 + 3], hh.w, pw); pc = fmaf(wc2[l4 * 4 + 3], hh.w, pc);
      }
      pw = __fadd_rn(pw, __shfl_xor(pw, 1, 64));
      pc = __fadd_rn(pc, __shfl_xor(pc, 1, 64));
      pw = __fadd_rn(pw, __shfl_xor(pw, 2, 64));
      pc = __fadd_rn(pc, __shfl_xor(pc, 2, 64));
      if (g == 0) {
        wc2v[cq] = pc;
        float Ck = fmaf(A0a[cq], fuelR, fmaf(A1a[cq], timeR, __fadd_rn(D0a[cq], pw)));
        kbi[2 * (cq & 63) + (cq >> 6)].w = Ck;
      }
    }
    __syncthreads();                               // b2
    // ---- E: mask, drow fill, tanh loop, gumbel, fused reduce ---- [(s,hf)]
    float pe, lg;
    if (hf == 0) drowX[s] = dnextR;   // row of node niR (prev step's pick)
    bool mk;
    if (t == 0) mk = true;
    else {
      bool fok = fuelR >= __fmul_rn(0.2f, __fadd_rn(dnextR, dbaR));
      bool tok = timeR >= __fdiv_rn(__fadd_rn(dnextR, d2dR), 60.0f);
      bool cust = (demreg > 0.0f) && fok && tok;
      mk = (s <= 3) ? (s != niR) : cust;
      if (s == 0) mk = true;
    }
    {
      unsigned rb;
      { unsigned o0, o1; tf2x32(kAs[t], kBs[t], 0u, (unsigned)(b * SEQN + s), o0, o1); rb = o0 ^ o1; }
      float f = __uint_as_float((rb >> 9) | 0x3f800000u) - 1.0f;
      float u = fmaxf(TINYF, __fadd_rn(f, TINYF));
      float gmb = -logf(-logf(u));
      float acc = 0.0f;
      const float4* v4p = (const float4*)v4f;
#pragma unroll 4
      for (int j = 0; j < 16; ++j) {
        float4 vv = v4p[2 * j + hf];
        float4 kb;
        float Tv;
        kb = kbi[8 * j + 0 + hf];
        Tv = fmaf(kb.x, xreg, fmaf(kb.y, yreg, fmaf(kb.z, demreg, kb.w)));
        acc = fmaf(vv.x, fast_tanh(Tv), acc);
        kb = kbi[8 * j + 2 + hf];
        Tv = fmaf(kb.x, xreg, fmaf(kb.y, yreg, fmaf(kb.z, demreg, kb.w)));
        acc = fmaf(vv.y, fast_tanh(Tv), acc);
        kb = kbi[8 * j + 4 + hf];
        Tv = fmaf(kb.x, xreg, fmaf(kb.y, yreg, fmaf(kb.z, demreg, kb.w)));
        acc = fmaf(vv.z, fast_tanh(Tv), acc);
        kb = kbi[8 * j + 6 + hf];
        Tv = fmaf(kb.x, xreg, fmaf(kb.y, yreg, fmaf(kb.z, demreg, kb.w)));
        acc = fmaf(vv.w, fast_tanh(Tv), acc);
      }
      float e = __fadd_rn(acc, __shfl_xor(acc, 1, 64));
      lg = mk ? e : NEGV;
      pe = __builtin_amdgcn_exp2f(__fmul_rn(lg, LOG2E));
      float sc = __fadd_rn(gmb, lg);
      float av = sc; int ai = s;
      float S = pe, px = __fmul_rn(pe, xreg), py = __fmul_rn(pe, yreg);
#pragma unroll
      for (int off = 2; off < 64; off <<= 1) {
        float ov = __shfl_xor(av, off, 64);
        int   oi = __shfl_xor(ai, off, 64);
        if (ov > av || (ov == av && oi < ai)) { av = ov; ai = oi; }
        S  = __fadd_rn(S,  __shfl_xor(S,  off, 64));
        px = __fadd_rn(px, __shfl_xor(px, off, 64));
        py = __fadd_rn(py, __shfl_xor(py, off, 64));
      }
      if (lane == 0) { rv[wv] = av; ri[wv] = ai; rS[wv] = S; rpx[wv] = px; rpy[wv] = py; }
    }
    __syncthreads();                               // b3
    // ---- FG: final combine, state update, outputs, h_new, drow prefetch ----
    {
      float bv = rv[0]; int bi = ri[0];
#pragma unroll
      for (int w = 1; w < 8; ++w)
        if (rv[w] > bv) { bv = rv[w]; bi = ri[w]; }
      int ni = bi;
      dnextR = distb[(size_t)ni * SEQN + s];       // issued now, consumed next E
      float S = rS[0], px = rpx[0], py = rpy[0];
#pragma unroll
      for (int w = 1; w < 8; ++w) {
        S = __fadd_rn(S, rS[w]); px = __fadd_rn(px, rpx[w]); py = __fadd_rn(py, rpy[w]);
      }
      float dis = drowX[ni];
      float fl = __fsub_rn(fuelR, __fmul_rn(0.2f, dis));
      float tm = __fsub_rn(timeR, __fdiv_rn(dis, 60.0f));
      if (ni <= 3) fl = 60.0f;
      if (ni == 0) tm = 11.0f;
      fuelR = fl; timeR = tm;
      if (s == ni && ni > 3) demreg = 0.0f;
      float2 dxy = xy2[ni];
      decxR = dxy.x; decyR = dxy.y;
      float pr = __fdiv_rn(pe, S);
      if (hf == 0) out_probs[((size_t)b * T + t) * SEQN + s] = pr;
      if (s == ni && hf == 0) {
        out_tours[(size_t)b * T + t] = (float)ni;
        out_logps[(size_t)b * T + t] = __fsub_rn(lg, logf(S));
      }
      if (tid < HD) {
        float cx = __fdiv_rn(px, S), cy = __fdiv_rn(py, S);
        float ctxd = fmaf(C0a[tid], cx, fmaf(C1a[tid], cy, C2a[tid]));
        float val = __fadd_rn(__fadd_rn(ctxd, wc2v[tid]), bca[tid]);
        hstm[tid] = fast_tanh(val);
      }
      niR = ni;
    }
    __syncthreads();                               // b4
  }
}

extern "C" void kernel_launch(void* const* d_in, const int* in_sizes, int n_in,
                              void* d_out, int out_size, void* d_ws, size_t ws_size,
                              hipStream_t stream) {
  (void)in_sizes; (void)n_in; (void)out_size; (void)d_ws; (void)ws_size;
  evrp_kernel<<<dim3(BSZ), dim3(512), 0, stream>>>(
      (const float*)d_in[0],  (const float*)d_in[1],  (const float*)d_in[2],
      (const float*)d_in[3],  (const float*)d_in[4],  (const float*)d_in[5],
      (const float*)d_in[6],  (const float*)d_in[7],  (const float*)d_in[8],
      (const float*)d_in[9],  (const float*)d_in[10], (const float*)d_in[11],
      (const float*)d_in[12], (const float*)d_in[13], (const float*)d_in[14],
      (const int*)d_in[15],   (float*)d_out);
}

// Round 5
// 984.256 us; speedup vs baseline: 2.5902x; 1.0277x over previous
//
#include <hip/hip_runtime.h>
#include <cmath>

// EVRP solver rollout — one block per batch element, 128-step decode on-device.
// PRNG: JAX threefry2x32 partitionable scheme (verified). Discrete state path
// (fuel/time/demand/mask) is bit-exact vs jnp f32; logit path is analog.
// R5: P[s][k] = B0x+B1y+A2*dem precomputed to dynamic LDS (valid because any
// node whose demand changes becomes permanently masked); fast v_log gumbel.
#define BSZ 256
#define SEQN 256
#define HD 128
#define NEGV -1000000000.0f
#define TINYF 1.17549435e-38f
#define LOG2E 1.4426950408889634f
#define LN2F 0.6931471805599453f

static __device__ __forceinline__ void tf2x32(unsigned k0, unsigned k1,
                                              unsigned x0, unsigned x1,
                                              unsigned &o0, unsigned &o1) {
  unsigned ks2 = k0 ^ k1 ^ 0x1BD11BDAu;
#define TFR(r) { x0 += x1; x1 = (x1 << (r)) | (x1 >> (32 - (r))); x1 ^= x0; }
  x0 += k0; x1 += k1;
  TFR(13) TFR(15) TFR(26) TFR(6)
  x0 += k1; x1 += ks2 + 1u;
  TFR(17) TFR(29) TFR(16) TFR(24)
  x0 += ks2; x1 += k0 + 2u;
  TFR(13) TFR(15) TFR(26) TFR(6)
  x0 += k0; x1 += k1 + 3u;
  TFR(17) TFR(29) TFR(16) TFR(24)
  x0 += k1; x1 += ks2 + 4u;
  TFR(13) TFR(15) TFR(26) TFR(6)
  x0 += ks2; x1 += k0 + 5u;
#undef TFR
  o0 = x0; o1 = x1;
}

static __device__ __forceinline__ float fast_tanh(float x) {
  float y = __fmul_rn(x, 2.885390081777927f);                 // 2*log2(e)*x
  float ay = __int_as_float(__float_as_int(y) | 0x80000000u); // -|y|
  float q = __builtin_amdgcn_exp2f(ay);
  float r = __fmul_rn(__fsub_rn(1.0f, q),
                      __builtin_amdgcn_rcpf(__fadd_rn(1.0f, q)));
  unsigned sgn = (unsigned)__float_as_int(x) & 0x80000000u;
  return __int_as_float(__float_as_int(r) | sgn);
}

static __device__ __forceinline__ float fast_sig(float x) {
  float q = __builtin_amdgcn_exp2f(__fmul_rn(x, -LOG2E));
  return __builtin_amdgcn_rcpf(__fadd_rn(1.0f, q));
}

// ln(x) via v_log_f32 (log2) — ~1e-7 rel err, analog path only.
static __device__ __forceinline__ float fast_ln(float x) {
  return __fmul_rn(__builtin_amdgcn_logf(x), LN2F);
}

__global__ __launch_bounds__(512, 2) void evrp_kernel(
    const float* __restrict__ statc, const float* __restrict__ dyn,
    const float* __restrict__ dist,  const float* __restrict__ W_s,
    const float* __restrict__ b_s,   const float* __restrict__ W_d,
    const float* __restrict__ b_d,   const float* __restrict__ W_i,
    const float* __restrict__ W_h,   const float* __restrict__ b_i,
    const float* __restrict__ b_h,   const float* __restrict__ W_att,
    const float* __restrict__ v_att, const float* __restrict__ W_c,
    const float* __restrict__ b_c,   const int* __restrict__ steps_p,
    float* __restrict__ out) {
  const int b = blockIdx.x;
  const int tid = threadIdx.x;
  const int T = steps_p[0];
  const int lane = tid & 63;
  const int wv = tid >> 6;
  const int s = tid >> 1, hf = tid & 1;      // E/FG mapping
  const int cq = tid >> 2, g = tid & 3;      // AB/C mapping

  extern __shared__ __align__(16) float4 Pdyn[];   // [16 chunks][512 sl] = 128KB

  __shared__ __align__(16) float  B0a[HD], B1a[HD], A2a[HD];
  __shared__ __align__(16) float  Ct[HD], Vt[HD];
  __shared__ __align__(16) float  hstm[HD], hlm[HD], wc2v[HD];
  __shared__ __align__(16) float  A0a[HD], A1a[HD], D0a[HD];
  __shared__ __align__(16) float  C0a[HD], C1a[HD], C2a[HD], bca[HD];
  __shared__ __align__(16) float2 xy2[SEQN];
  __shared__ __align__(16) float  drowX[SEQN];
  __shared__ __align__(16) unsigned kAs[256], kBs[256];
  __shared__ __align__(16) float ws0[HD], ws1[HD], bsv[HD];
  __shared__ __align__(16) float wd0[HD], wd1[HD], wd2[HD], bdv[HD];
  __shared__ float rv[8], rS[8], rpx[8], rpy[8];
  __shared__ int ri[8];

  const float* distb = dist + (size_t)b * SEQN * SEQN;

  // ---------------- prologue: loads ----------------
  if (tid < HD) {
    ws0[tid] = W_s[2 * tid]; ws1[tid] = W_s[2 * tid + 1]; bsv[tid] = b_s[tid];
    wd0[tid] = W_d[3 * tid]; wd1[tid] = W_d[3 * tid + 1]; wd2[tid] = W_d[3 * tid + 2];
    bdv[tid] = b_d[tid]; bca[tid] = b_c[tid];
    hstm[tid] = 0.0f;
  }
  float xreg = statc[b * 2 * SEQN + s];
  float yreg = statc[b * 2 * SEQN + SEQN + s];
  float demreg = dyn[b * 3 * SEQN + 2 * SEQN + s];
  float d2dR = distb[(size_t)s * SEQN];
  float dbaR;
  {
    float d10 = distb[1 * SEQN + 0], d20 = distb[2 * SEQN + 0], d30 = distb[3 * SEQN + 0];
    float d1s = distb[1 * SEQN + s], d2s = distb[2 * SEQN + s], d3s = distb[3 * SEQN + s];
    float m = fminf(fminf(__fadd_rn(d10, d1s), __fadd_rn(d20, d2s)), __fadd_rn(d30, d3s));
    dbaR = (s == 0) ? 0.0f : m;
  }
  float dnextR = distb[s];       // row 0 — fills drowX at E_0
  if (hf == 0) xy2[s] = make_float2(xreg, yreg);
  float fuelR = dyn[b * 3 * SEQN + 0];
  float timeR = dyn[b * 3 * SEQN + SEQN + 0];
  float cstR = 0.0f;
  int niR = 0;
  for (int tt = tid; tt < 256; tt += 512) {
    unsigned a0, a1; tf2x32(0u, 1u, 0u, (unsigned)tt, a0, a1);
    kAs[tt] = a0; kBs[tt] = a1;
  }
  __syncthreads();

  // ---------------- prologue: folds + register weights ----------------
  if (tid < HD) {
    int k = tid;
    const float* row = W_att + (size_t)k * 384;
    float B0 = 0, B1 = 0, B2 = 0, A0 = 0, A1 = 0, A2 = 0, A3 = 0;
    for (int c = 0; c < HD; ++c) {
      float w1 = row[c], w2 = row[128 + c];
      B0 = fmaf(w1, ws0[c], B0); B1 = fmaf(w1, ws1[c], B1); B2 = fmaf(w1, bsv[c], B2);
      A0 = fmaf(w2, wd0[c], A0); A1 = fmaf(w2, wd1[c], A1);
      A2 = fmaf(w2, wd2[c], A2); A3 = fmaf(w2, bdv[c], A3);
    }
    B0a[k] = B0; B1a[k] = B1; A2a[k] = A2; Vt[k] = v_att[k];
    A0a[k] = A0; A1a[k] = A1; D0a[k] = __fadd_rn(B2, A3);
  } else if (tid < 2 * HD) {
    int o = tid - HD;
    const float* row = W_c + (size_t)o * 256;
    float C0 = 0, C1 = 0, C2 = 0;
    for (int c = 0; c < HD; ++c) {
      float w = row[c];
      C0 = fmaf(w, ws0[c], C0); C1 = fmaf(w, ws1[c], C1); C2 = fmaf(w, bsv[c], C2);
    }
    C0a[o] = C0; C1a[o] = C1; C2a[o] = C2;
  }
  float gp0 = 0, gp1 = 0, gp2 = 0, gpw;
  {
    int j = g * HD + cq;
    const float* row = W_i + (size_t)j * HD;
    for (int c = 0; c < HD; ++c) {
      float w = row[c];
      gp0 = fmaf(w, ws0[c], gp0); gp1 = fmaf(w, ws1[c], gp1); gp2 = fmaf(w, bsv[c], gp2);
    }
    gpw = __fadd_rn(b_i[j], b_h[j]);
  }
  // register-resident weights — loaded once, then made OPAQUE so the
  // allocator cannot rematerialize/stream them from memory each step.
  float whreg[HD];
  {
    int j = g * HD + cq;
#pragma unroll
    for (int c = 0; c < HD; ++c) whreg[c] = W_h[(size_t)j * HD + c];
  }
  float wah[32], wc2[32];
#pragma unroll
  for (int i = 0; i < 32; ++i) {
    wah[i] = W_att[(size_t)cq * 384 + 256 + g * 32 + i];
    wc2[i] = W_c[(size_t)cq * 256 + HD + g * 32 + i];
  }
#pragma unroll
  for (int c = 0; c < HD; c += 4)
    asm volatile("" : "+v"(whreg[c]), "+v"(whreg[c + 1]),
                      "+v"(whreg[c + 2]), "+v"(whreg[c + 3]));
#pragma unroll
  for (int i = 0; i < 32; i += 4)
    asm volatile("" : "+v"(wah[i]), "+v"(wah[i + 1]),
                      "+v"(wah[i + 2]), "+v"(wah[i + 3]));
#pragma unroll
  for (int i = 0; i < 32; i += 4)
    asm volatile("" : "+v"(wc2[i]), "+v"(wc2[i + 1]),
                      "+v"(wc2[i + 2]), "+v"(wc2[i + 3]));
  __syncthreads();

  // ---------------- prologue: fill P[s][k] (constant over rollout) ----------
  // P[s][k] = B0[k]*x_s + B1[k]*y_s + A2[k]*dem_s; any node whose dem changes
  // becomes permanently masked, so this is rollout-constant where it matters.
  // Layout: chunk i=(k>>2)&15 major, sl=s*2+(k>>6): lane-consecutive for E.
  for (int idx = tid; idx < SEQN * HD; idx += 512) {
    int ss = idx >> 7, k = idx & 127;
    float2 pxy = xy2[ss];
    float dm = dyn[b * 3 * SEQN + 2 * SEQN + ss];
    float pv = fmaf(B0a[k], pxy.x, fmaf(B1a[k], pxy.y, __fmul_rn(A2a[k], dm)));
    ((float*)Pdyn)[(((k >> 2) & 15) << 11) + ((ss * 2 + (k >> 6)) << 2) + (k & 3)] = pv;
  }
  __syncthreads();

  float decxR = xy2[0].x, decyR = xy2[0].y;

  float* out_probs = out;
  float* out_tours = out + (size_t)BSZ * T * SEQN;
  float* out_logps = out_tours + (size_t)BSZ * T;

  const float4* Pp = Pdyn + (s * 2 + hf);   // + chunk*512
  const float* CtH = Ct + hf * 64;
  const float* VtH = Vt + hf * 64;

  // ---------------- decode loop (4 barriers/step) ----------------
  for (int t = 0; t < T; ++t) {
    // ---- AB: gates + LSTM via quad shuffle ---- [all 512; (cq,g)]
    {
      float m0 = 0, m1 = 0, m2 = 0, m3 = 0;
      const float4* h4 = (const float4*)hstm;
#pragma unroll
      for (int c4 = 0; c4 < HD / 4; ++c4) {
        float4 hh = h4[c4];
        m0 = fmaf(whreg[4 * c4 + 0], hh.x, m0);
        m1 = fmaf(whreg[4 * c4 + 1], hh.y, m1);
        m2 = fmaf(whreg[4 * c4 + 2], hh.z, m2);
        m3 = fmaf(whreg[4 * c4 + 3], hh.w, m3);
      }
      float md = fmaf(gp0, decxR, fmaf(gp1, decyR, gp2));
      float V = __fadd_rn(__fadd_rn(md, __fadd_rn(__fadd_rn(m0, m1), __fadd_rn(m2, m3))), gpw);
      float sg = fast_sig(V), th = fast_tanh(V);
      float q = (g == 2) ? th : sg;
      float u1 = __shfl_xor(q, 1, 64);
      float u2 = __shfl_xor(q, 2, 64);
      float u3 = __shfl_xor(q, 3, 64);
      float qi = (g == 0) ? q  : (g == 1) ? u1 : (g == 2) ? u2 : u3;
      float qf = (g == 0) ? u1 : (g == 1) ? q  : (g == 2) ? u3 : u2;
      float qg = (g == 0) ? u2 : (g == 1) ? u3 : (g == 2) ? q  : u1;
      float qo = (g == 0) ? u3 : (g == 1) ? u2 : (g == 2) ? u1 : q;
      float cn = __fadd_rn(__fmul_rn(qf, cstR), __fmul_rn(qi, qg));
      cstR = cn;
      float hv = __fmul_rn(qo, fast_tanh(cn));
      if (g == 0) hlm[(cq & 96) | ((cq & 31) ^ ((cq >> 5) << 3))] = hv;
    }
    __syncthreads();                               // b1
    // ---- C: W_att_h@h, W_c2@h; write Ck into Ct ---- [all 512; (cq,g)]
    {
      float pw = 0.0f, pc = 0.0f;
      const float4* hl4 = (const float4*)hlm;
#pragma unroll
      for (int l4 = 0; l4 < 8; ++l4) {
        float4 hh = hl4[(g << 3) + (l4 ^ (g << 1))];   // XOR-swizzled, conflict-free
        pw = fmaf(wah[l4 * 4 + 0], hh.x, pw); pc = fmaf(wc2[l4 * 4 + 0], hh.x, pc);
        pw = fmaf(wah[l4 * 4 + 1], hh.y, pw); pc = fmaf(wc2[l4 * 4 + 1], hh.y, pc);
        pw = fmaf(wah[l4 * 4 + 2], hh.z, pw); pc = fmaf(wc2[l4 * 4 + 2], hh.z, pc);
        pw = fmaf(wah[l4 * 4 + 3], hh.w, pw); pc = fmaf(wc2[l4 * 4 + 3], hh.w, pc);
      }
      pw = __fadd_rn(pw, __shfl_xor(pw, 1, 64));
      pc = __fadd_rn(pc, __shfl_xor(pc, 1, 64));
      pw = __fadd_rn(pw, __shfl_xor(pw, 2, 64));
      pc = __fadd_rn(pc, __shfl_xor(pc, 2, 64));
      if (g == 0) {
        wc2v[cq] = pc;
        Ct[cq] = fmaf(A0a[cq], fuelR, fmaf(A1a[cq], timeR, __fadd_rn(D0a[cq], pw)));
      }
    }
    __syncthreads();                               // b2
    // ---- E: mask, drow fill, tanh loop, gumbel, fused reduce ---- [(s,hf)]
    float pe, lg;
    if (hf == 0) drowX[s] = dnextR;   // row of node niR (prev step's pick)
    bool mk;
    if (t == 0) mk = true;
    else {
      bool fok = fuelR >= __fmul_rn(0.2f, __fadd_rn(dnextR, dbaR));
      bool tok = timeR >= __fdiv_rn(__fadd_rn(dnextR, d2dR), 60.0f);
      bool cust = (demreg > 0.0f) && fok && tok;
      mk = (s <= 3) ? (s != niR) : cust;
      if (s == 0) mk = true;
    }
    {
      unsigned rb;
      { unsigned o0, o1; tf2x32(kAs[t], kBs[t], 0u, (unsigned)(b * SEQN + s), o0, o1); rb = o0 ^ o1; }
      float f = __uint_as_float((rb >> 9) | 0x3f800000u) - 1.0f;
      float u = fmaxf(TINYF, __fadd_rn(f, TINYF));
      float gmb = -fast_ln(-fast_ln(u));
      float acc = 0.0f;
#pragma unroll
      for (int i = 0; i < 16; ++i) {
        float4 pv = Pp[i << 9];
        float4 ct = *(const float4*)(CtH + 4 * i);
        float4 vv = *(const float4*)(VtH + 4 * i);
        acc = fmaf(vv.x, fast_tanh(__fadd_rn(pv.x, ct.x)), acc);
        acc = fmaf(vv.y, fast_tanh(__fadd_rn(pv.y, ct.y)), acc);
        acc = fmaf(vv.z, fast_tanh(__fadd_rn(pv.z, ct.z)), acc);
        acc = fmaf(vv.w, fast_tanh(__fadd_rn(pv.w, ct.w)), acc);
      }
      float e = __fadd_rn(acc, __shfl_xor(acc, 1, 64));
      lg = mk ? e : NEGV;
      pe = __builtin_amdgcn_exp2f(__fmul_rn(lg, LOG2E));
      float sc = __fadd_rn(gmb, lg);
      float av = sc; int ai = s;
      float S = pe, px = __fmul_rn(pe, xreg), py = __fmul_rn(pe, yreg);
#pragma unroll
      for (int off = 2; off < 64; off <<= 1) {
        float ov = __shfl_xor(av, off, 64);
        int   oi = __shfl_xor(ai, off, 64);
        if (ov > av || (ov == av && oi < ai)) { av = ov; ai = oi; }
        S  = __fadd_rn(S,  __shfl_xor(S,  off, 64));
        px = __fadd_rn(px, __shfl_xor(px, off, 64));
        py = __fadd_rn(py, __shfl_xor(py, off, 64));
      }
      if (lane == 0) { rv[wv] = av; ri[wv] = ai; rS[wv] = S; rpx[wv] = px; rpy[wv] = py; }
    }
    __syncthreads();                               // b3
    // ---- FG: final combine, state update, outputs, h_new, drow prefetch ----
    {
      float bv = rv[0]; int bi = ri[0];
#pragma unroll
      for (int w = 1; w < 8; ++w)
        if (rv[w] > bv) { bv = rv[w]; bi = ri[w]; }
      int ni = bi;
      dnextR = distb[(size_t)ni * SEQN + s];       // issued now, consumed next E
      float S = rS[0], px = rpx[0], py = rpy[0];
#pragma unroll
      for (int w = 1; w < 8; ++w) {
        S = __fadd_rn(S, rS[w]); px = __fadd_rn(px, rpx[w]); py = __fadd_rn(py, rpy[w]);
      }
      float dis = drowX[ni];
      float fl = __fsub_rn(fuelR, __fmul_rn(0.2f, dis));
      float tm = __fsub_rn(timeR, __fdiv_rn(dis, 60.0f));
      if (ni <= 3) fl = 60.0f;
      if (ni == 0) tm = 11.0f;
      fuelR = fl; timeR = tm;
      if (s == ni && ni > 3) demreg = 0.0f;
      float2 dxy = xy2[ni];
      decxR = dxy.x; decyR = dxy.y;
      float pr = __fdiv_rn(pe, S);
      if (hf == 0) out_probs[((size_t)b * T + t) * SEQN + s] = pr;
      if (s == ni && hf == 0) {
        out_tours[(size_t)b * T + t] = (float)ni;
        out_logps[(size_t)b * T + t] = __fsub_rn(lg, fast_ln(S));
      }
      if (tid < HD) {
        float cx = __fdiv_rn(px, S), cy = __fdiv_rn(py, S);
        float ctxd = fmaf(C0a[tid], cx, fmaf(C1a[tid], cy, C2a[tid]));
        float val = __fadd_rn(__fadd_rn(ctxd, wc2v[tid]), bca[tid]);
        hstm[tid] = fast_tanh(val);
      }
      niR = ni;
    }
    __syncthreads();                               // b4
  }
}

extern "C" void kernel_launch(void* const* d_in, const int* in_sizes, int n_in,
                              void* d_out, int out_size, void* d_ws, size_t ws_size,
                              hipStream_t stream) {
  (void)in_sizes; (void)n_in; (void)out_size; (void)d_ws; (void)ws_size;
  (void)hipFuncSetAttribute((const void*)evrp_kernel,
                            hipFuncAttributeMaxDynamicSharedMemorySize,
                            SEQN * HD * 4);
  evrp_kernel<<<dim3(BSZ), dim3(512), SEQN * HD * 4, stream>>>(
      (const float*)d_in[0],  (const float*)d_in[1],  (const float*)d_in[2],
      (const float*)d_in[3],  (const float*)d_in[4],  (const float*)d_in[5],
      (const float*)d_in[6],  (const float*)d_in[7],  (const float*)d_in[8],
      (const float*)d_in[9],  (const float*)d_in[10], (const float*)d_in[11],
      (const float*)d_in[12], (const float*)d_in[13], (const float*)d_in[14],
      (const int*)d_in[15],   (float*)d_out);
}

// Round 7
// 930.293 us; speedup vs baseline: 2.7404x; 1.0580x over previous
//
#include <hip/hip_runtime.h>
#include <cmath>

// EVRP solver rollout — one block per batch element, 128-step decode on-device.
// PRNG: JAX threefry2x32 partitionable scheme (verified). Discrete state path
// (fuel/time/demand/mask) is bit-exact vs jnp f32; logit path is analog.
// R7: packed-FP32 via NATIVE v2f codegen (no VOP3P inline asm — R6's NaN).
#define BSZ 256
#define SEQN 256
#define HD 128
#define NEGV -1000000000.0f
#define TINYF 1.17549435e-38f
#define LOG2E 1.4426950408889634f
#define LN2F 0.6931471805599453f

typedef float v2f __attribute__((ext_vector_type(2)));

static __device__ __forceinline__ v2f mk2(float a, float b) {
  v2f r; r.x = a; r.y = b; return r;
}
static __device__ __forceinline__ v2f fma2(v2f a, v2f b, v2f c) {
  return __builtin_elementwise_fma(a, b, c);
}

static __device__ __forceinline__ void tf2x32(unsigned k0, unsigned k1,
                                              unsigned x0, unsigned x1,
                                              unsigned &o0, unsigned &o1) {
  unsigned ks2 = k0 ^ k1 ^ 0x1BD11BDAu;
#define TFR(r) { x0 += x1; x1 = (x1 << (r)) | (x1 >> (32 - (r))); x1 ^= x0; }
  x0 += k0; x1 += k1;
  TFR(13) TFR(15) TFR(26) TFR(6)
  x0 += k1; x1 += ks2 + 1u;
  TFR(17) TFR(29) TFR(16) TFR(24)
  x0 += ks2; x1 += k0 + 2u;
  TFR(13) TFR(15) TFR(26) TFR(6)
  x0 += k0; x1 += k1 + 3u;
  TFR(17) TFR(29) TFR(16) TFR(24)
  x0 += k1; x1 += ks2 + 4u;
  TFR(13) TFR(15) TFR(26) TFR(6)
  x0 += ks2; x1 += k0 + 5u;
#undef TFR
  o0 = x0; o1 = x1;
}

static __device__ __forceinline__ float fast_tanh(float x) {
  float y = __fmul_rn(x, 2.885390081777927f);                 // 2*log2(e)*x
  float ay = __int_as_float(__float_as_int(y) | 0x80000000u); // -|y|
  float q = __builtin_amdgcn_exp2f(ay);
  float r = __fmul_rn(__fsub_rn(1.0f, q),
                      __builtin_amdgcn_rcpf(__fadd_rn(1.0f, q)));
  unsigned sgn = (unsigned)__float_as_int(x) & 0x80000000u;
  return __int_as_float(__float_as_int(r) | sgn);
}

static __device__ __forceinline__ float fast_sig(float x) {
  float q = __builtin_amdgcn_exp2f(__fmul_rn(x, -LOG2E));
  return __builtin_amdgcn_rcpf(__fadd_rn(1.0f, q));
}

// ln(x) via v_log_f32 (log2) — ~1e-7 rel err, analog path only.
static __device__ __forceinline__ float fast_ln(float x) {
  return __fmul_rn(__builtin_amdgcn_logf(x), LN2F);
}

// tanh(x) = (s-1)/(s+1), s = e^{2x} clamped — packable, finite for finite x.
static __device__ __forceinline__ v2f tanh2(v2f x) {
  v2f y = x * mk2(2.885390081777927f, 2.885390081777927f);
  y = __builtin_elementwise_min(y, mk2(48.0f, 48.0f));
  v2f s; s.x = __builtin_amdgcn_exp2f(y.x); s.y = __builtin_amdgcn_exp2f(y.y);
  v2f n = s + mk2(-1.0f, -1.0f);
  v2f d = s + mk2(1.0f, 1.0f);
  v2f r; r.x = __builtin_amdgcn_rcpf(d.x); r.y = __builtin_amdgcn_rcpf(d.y);
  return n * r;
}

__global__ __launch_bounds__(512, 2) void evrp_kernel(
    const float* __restrict__ statc, const float* __restrict__ dyn,
    const float* __restrict__ dist,  const float* __restrict__ W_s,
    const float* __restrict__ b_s,   const float* __restrict__ W_d,
    const float* __restrict__ b_d,   const float* __restrict__ W_i,
    const float* __restrict__ W_h,   const float* __restrict__ b_i,
    const float* __restrict__ b_h,   const float* __restrict__ W_att,
    const float* __restrict__ v_att, const float* __restrict__ W_c,
    const float* __restrict__ b_c,   const int* __restrict__ steps_p,
    float* __restrict__ out) {
  const int b = blockIdx.x;
  const int tid = threadIdx.x;
  const int T = steps_p[0];
  const int lane = tid & 63;
  const int wv = tid >> 6;
  const int s = tid >> 1, hf = tid & 1;      // E/FG mapping
  const int cq = tid >> 2, g = tid & 3;      // AB/C mapping

  extern __shared__ __align__(16) float4 Pdyn[];   // [16 chunks][512 sl] = 128KB

  __shared__ __align__(16) float  B0a[HD], B1a[HD], A2a[HD];
  __shared__ __align__(16) float  Ct[HD], Vt[HD];
  __shared__ __align__(16) float  hstm[HD], hlm[HD], wc2v[HD];
  __shared__ __align__(16) float  A0a[HD], A1a[HD], D0a[HD];
  __shared__ __align__(16) float  C0a[HD], C1a[HD], C2a[HD], bca[HD];
  __shared__ __align__(16) float2 xy2[SEQN];
  __shared__ __align__(16) float  drowX[SEQN];
  __shared__ __align__(16) unsigned kAs[256], kBs[256];
  __shared__ __align__(16) float ws0[HD], ws1[HD], bsv[HD];
  __shared__ __align__(16) float wd0[HD], wd1[HD], wd2[HD], bdv[HD];
  __shared__ float rv[8], rS[8], rpx[8], rpy[8];
  __shared__ int ri[8];

  const float* distb = dist + (size_t)b * SEQN * SEQN;

  // ---------------- prologue: loads ----------------
  if (tid < HD) {
    ws0[tid] = W_s[2 * tid]; ws1[tid] = W_s[2 * tid + 1]; bsv[tid] = b_s[tid];
    wd0[tid] = W_d[3 * tid]; wd1[tid] = W_d[3 * tid + 1]; wd2[tid] = W_d[3 * tid + 2];
    bdv[tid] = b_d[tid]; bca[tid] = b_c[tid];
    hstm[tid] = 0.0f;
  }
  float xreg = statc[b * 2 * SEQN + s];
  float yreg = statc[b * 2 * SEQN + SEQN + s];
  float demreg = dyn[b * 3 * SEQN + 2 * SEQN + s];
  float d2dR = distb[(size_t)s * SEQN];
  float dbaR;
  {
    float d10 = distb[1 * SEQN + 0], d20 = distb[2 * SEQN + 0], d30 = distb[3 * SEQN + 0];
    float d1s = distb[1 * SEQN + s], d2s = distb[2 * SEQN + s], d3s = distb[3 * SEQN + s];
    float m = fminf(fminf(__fadd_rn(d10, d1s), __fadd_rn(d20, d2s)), __fadd_rn(d30, d3s));
    dbaR = (s == 0) ? 0.0f : m;
  }
  float dnextR = distb[s];       // row 0 — fills drowX at E_0
  if (hf == 0) xy2[s] = make_float2(xreg, yreg);
  float fuelR = dyn[b * 3 * SEQN + 0];
  float timeR = dyn[b * 3 * SEQN + SEQN + 0];
  float cstR = 0.0f;
  int niR = 0;
  for (int tt = tid; tt < 256; tt += 512) {
    unsigned a0, a1; tf2x32(0u, 1u, 0u, (unsigned)tt, a0, a1);
    kAs[tt] = a0; kBs[tt] = a1;
  }
  __syncthreads();

  // ---------------- prologue: folds + register weights ----------------
  if (tid < HD) {
    int k = tid;
    const float* row = W_att + (size_t)k * 384;
    float B0 = 0, B1 = 0, B2 = 0, A0 = 0, A1 = 0, A2 = 0, A3 = 0;
    for (int c = 0; c < HD; ++c) {
      float w1 = row[c], w2 = row[128 + c];
      B0 = fmaf(w1, ws0[c], B0); B1 = fmaf(w1, ws1[c], B1); B2 = fmaf(w1, bsv[c], B2);
      A0 = fmaf(w2, wd0[c], A0); A1 = fmaf(w2, wd1[c], A1);
      A2 = fmaf(w2, wd2[c], A2); A3 = fmaf(w2, bdv[c], A3);
    }
    B0a[k] = B0; B1a[k] = B1; A2a[k] = A2; Vt[k] = v_att[k];
    A0a[k] = A0; A1a[k] = A1; D0a[k] = __fadd_rn(B2, A3);
  } else if (tid < 2 * HD) {
    int o = tid - HD;
    const float* row = W_c + (size_t)o * 256;
    float C0 = 0, C1 = 0, C2 = 0;
    for (int c = 0; c < HD; ++c) {
      float w = row[c];
      C0 = fmaf(w, ws0[c], C0); C1 = fmaf(w, ws1[c], C1); C2 = fmaf(w, bsv[c], C2);
    }
    C0a[o] = C0; C1a[o] = C1; C2a[o] = C2;
  }
  float gp0 = 0, gp1 = 0, gp2 = 0, gpw;
  {
    int j = g * HD + cq;
    const float* row = W_i + (size_t)j * HD;
    for (int c = 0; c < HD; ++c) {
      float w = row[c];
      gp0 = fmaf(w, ws0[c], gp0); gp1 = fmaf(w, ws1[c], gp1); gp2 = fmaf(w, bsv[c], gp2);
    }
    gpw = __fadd_rn(b_i[j], b_h[j]);
  }
  // register-resident weights as v2f pairs (native pk operands) — loaded once,
  // then made OPAQUE (empty asm, value-preserving) so the allocator cannot
  // rematerialize/stream them from memory each step.
  v2f whreg2[HD / 2];
  {
    int j = g * HD + cq;
#pragma unroll
    for (int c2 = 0; c2 < HD / 2; ++c2)
      whreg2[c2] = *(const v2f*)(&W_h[(size_t)j * HD + 2 * c2]);
  }
  v2f wah2[16], wc22[16];
#pragma unroll
  for (int i = 0; i < 16; ++i) {
    wah2[i] = *(const v2f*)(&W_att[(size_t)cq * 384 + 256 + g * 32 + 2 * i]);
    wc22[i] = *(const v2f*)(&W_c[(size_t)cq * 256 + HD + g * 32 + 2 * i]);
  }
#pragma unroll
  for (int c = 0; c < HD / 2; c += 2)
    asm volatile("" : "+v"(whreg2[c]), "+v"(whreg2[c + 1]));
#pragma unroll
  for (int i = 0; i < 16; i += 2) {
    asm volatile("" : "+v"(wah2[i]), "+v"(wah2[i + 1]));
    asm volatile("" : "+v"(wc22[i]), "+v"(wc22[i + 1]));
  }
  __syncthreads();

  // ---------------- prologue: fill P[s][k] (constant over rollout) ----------
  // P[s][k] = B0[k]*x_s + B1[k]*y_s + A2[k]*dem_s; any node whose dem changes
  // becomes permanently masked, so this is rollout-constant where it matters.
  for (int idx = tid; idx < SEQN * HD; idx += 512) {
    int ss = idx >> 7, k = idx & 127;
    float2 pxy = xy2[ss];
    float dm = dyn[b * 3 * SEQN + 2 * SEQN + ss];
    float pv = fmaf(B0a[k], pxy.x, fmaf(B1a[k], pxy.y, __fmul_rn(A2a[k], dm)));
    ((float*)Pdyn)[(((k >> 2) & 15) << 11) + ((ss * 2 + (k >> 6)) << 2) + (k & 3)] = pv;
  }
  __syncthreads();

  float decxR = xy2[0].x, decyR = xy2[0].y;

  float* out_probs = out;
  float* out_tours = out + (size_t)BSZ * T * SEQN;
  float* out_logps = out_tours + (size_t)BSZ * T;

  const float4* Pp = Pdyn + (s * 2 + hf);   // + chunk*512
  const float* CtH = Ct + hf * 64;
  const float* VtH = Vt + hf * 64;

  // ---------------- decode loop (4 barriers/step) ----------------
  for (int t = 0; t < T; ++t) {
    // ---- AB: gates + LSTM via quad shuffle ---- [all 512; (cq,g)]
    {
      v2f mA = mk2(0.f, 0.f), mB = mk2(0.f, 0.f);
      const float4* h4 = (const float4*)hstm;
#pragma unroll
      for (int c4 = 0; c4 < HD / 4; ++c4) {
        float4 hh = h4[c4];
        mA = fma2(whreg2[2 * c4],     mk2(hh.x, hh.y), mA);
        mB = fma2(whreg2[2 * c4 + 1], mk2(hh.z, hh.w), mB);
      }
      float md = fmaf(gp0, decxR, fmaf(gp1, decyR, gp2));
      float mh = __fadd_rn(__fadd_rn(mA.x, mA.y), __fadd_rn(mB.x, mB.y));
      float V = __fadd_rn(__fadd_rn(md, mh), gpw);
      float sg = fast_sig(V), th = fast_tanh(V);
      float q = (g == 2) ? th : sg;
      float u1 = __shfl_xor(q, 1, 64);
      float u2 = __shfl_xor(q, 2, 64);
      float u3 = __shfl_xor(q, 3, 64);
      float qi = (g == 0) ? q  : (g == 1) ? u1 : (g == 2) ? u2 : u3;
      float qf = (g == 0) ? u1 : (g == 1) ? q  : (g == 2) ? u3 : u2;
      float qg = (g == 0) ? u2 : (g == 1) ? u3 : (g == 2) ? q  : u1;
      float qo = (g == 0) ? u3 : (g == 1) ? u2 : (g == 2) ? u1 : q;
      float cn = __fadd_rn(__fmul_rn(qf, cstR), __fmul_rn(qi, qg));
      cstR = cn;
      float hv = __fmul_rn(qo, fast_tanh(cn));
      if (g == 0) hlm[(cq & 96) | ((cq & 31) ^ ((cq >> 5) << 3))] = hv;
    }
    __syncthreads();                               // b1
    // ---- C: W_att_h@h, W_c2@h; write Ck into Ct ---- [all 512; (cq,g)]
    {
      v2f pwA = mk2(0.f, 0.f), pwB = mk2(0.f, 0.f);
      v2f pcA = mk2(0.f, 0.f), pcB = mk2(0.f, 0.f);
      const float4* hl4 = (const float4*)hlm;
#pragma unroll
      for (int l4 = 0; l4 < 8; ++l4) {
        float4 hh = hl4[(g << 3) + (l4 ^ (g << 1))];   // XOR-swizzled, conflict-free
        v2f hA = mk2(hh.x, hh.y), hB = mk2(hh.z, hh.w);
        pwA = fma2(wah2[2 * l4],     hA, pwA);
        pwB = fma2(wah2[2 * l4 + 1], hB, pwB);
        pcA = fma2(wc22[2 * l4],     hA, pcA);
        pcB = fma2(wc22[2 * l4 + 1], hB, pcB);
      }
      float pw = __fadd_rn(__fadd_rn(pwA.x, pwA.y), __fadd_rn(pwB.x, pwB.y));
      float pc = __fadd_rn(__fadd_rn(pcA.x, pcA.y), __fadd_rn(pcB.x, pcB.y));
      pw = __fadd_rn(pw, __shfl_xor(pw, 1, 64));
      pc = __fadd_rn(pc, __shfl_xor(pc, 1, 64));
      pw = __fadd_rn(pw, __shfl_xor(pw, 2, 64));
      pc = __fadd_rn(pc, __shfl_xor(pc, 2, 64));
      if (g == 0) {
        wc2v[cq] = pc;
        Ct[cq] = fmaf(A0a[cq], fuelR, fmaf(A1a[cq], timeR, __fadd_rn(D0a[cq], pw)));
      }
    }
    __syncthreads();                               // b2
    // ---- E: mask, drow fill, tanh loop, gumbel, fused reduce ---- [(s,hf)]
    float pe, lg;
    if (hf == 0) drowX[s] = dnextR;   // row of node niR (prev step's pick)
    bool mk;
    if (t == 0) mk = true;
    else {
      bool fok = fuelR >= __fmul_rn(0.2f, __fadd_rn(dnextR, dbaR));
      bool tok = timeR >= __fdiv_rn(__fadd_rn(dnextR, d2dR), 60.0f);
      bool cust = (demreg > 0.0f) && fok && tok;
      mk = (s <= 3) ? (s != niR) : cust;
      if (s == 0) mk = true;
    }
    {
      unsigned rb;
      { unsigned o0, o1; tf2x32(kAs[t], kBs[t], 0u, (unsigned)(b * SEQN + s), o0, o1); rb = o0 ^ o1; }
      float f = __uint_as_float((rb >> 9) | 0x3f800000u) - 1.0f;
      float u = fmaxf(TINYF, __fadd_rn(f, TINYF));
      float gmb = -fast_ln(-fast_ln(u));
      v2f acc2 = mk2(0.f, 0.f);
#pragma unroll
      for (int i = 0; i < 16; ++i) {
        float4 pv = Pp[i << 9];
        float4 ct = *(const float4*)(CtH + 4 * i);
        float4 vv = *(const float4*)(VtH + 4 * i);
        v2f a0 = mk2(pv.x, pv.y) + mk2(ct.x, ct.y);
        acc2 = fma2(mk2(vv.x, vv.y), tanh2(a0), acc2);
        v2f a1 = mk2(pv.z, pv.w) + mk2(ct.z, ct.w);
        acc2 = fma2(mk2(vv.z, vv.w), tanh2(a1), acc2);
      }
      float acc = __fadd_rn(acc2.x, acc2.y);
      float e = __fadd_rn(acc, __shfl_xor(acc, 1, 64));
      lg = mk ? e : NEGV;
      pe = __builtin_amdgcn_exp2f(__fmul_rn(lg, LOG2E));
      float sc = __fadd_rn(gmb, lg);
      float av = sc; int ai = s;
      float S = pe, px = __fmul_rn(pe, xreg), py = __fmul_rn(pe, yreg);
#pragma unroll
      for (int off = 2; off < 64; off <<= 1) {
        float ov = __shfl_xor(av, off, 64);
        int   oi = __shfl_xor(ai, off, 64);
        if (ov > av || (ov == av && oi < ai)) { av = ov; ai = oi; }
        S  = __fadd_rn(S,  __shfl_xor(S,  off, 64));
        px = __fadd_rn(px, __shfl_xor(px, off, 64));
        py = __fadd_rn(py, __shfl_xor(py, off, 64));
      }
      if (lane == 0) { rv[wv] = av; ri[wv] = ai; rS[wv] = S; rpx[wv] = px; rpy[wv] = py; }
    }
    __syncthreads();                               // b3
    // ---- FG: final combine, state update, outputs, h_new, drow prefetch ----
    {
      float bv = rv[0]; int bi = ri[0];
#pragma unroll
      for (int w = 1; w < 8; ++w)
        if (rv[w] > bv) { bv = rv[w]; bi = ri[w]; }
      int ni = bi;
      dnextR = distb[(size_t)ni * SEQN + s];       // issued now, consumed next E
      float S = rS[0], px = rpx[0], py = rpy[0];
#pragma unroll
      for (int w = 1; w < 8; ++w) {
        S = __fadd_rn(S, rS[w]); px = __fadd_rn(px, rpx[w]); py = __fadd_rn(py, rpy[w]);
      }
      float dis = drowX[ni];
      float fl = __fsub_rn(fuelR, __fmul_rn(0.2f, dis));
      float tm = __fsub_rn(timeR, __fdiv_rn(dis, 60.0f));
      if (ni <= 3) fl = 60.0f;
      if (ni == 0) tm = 11.0f;
      fuelR = fl; timeR = tm;
      if (s == ni && ni > 3) demreg = 0.0f;
      float2 dxy = xy2[ni];
      decxR = dxy.x; decyR = dxy.y;
      float pr = __fdiv_rn(pe, S);
      if (hf == 0) out_probs[((size_t)b * T + t) * SEQN + s] = pr;
      if (s == ni && hf == 0) {
        out_tours[(size_t)b * T + t] = (float)ni;
        out_logps[(size_t)b * T + t] = __fsub_rn(lg, fast_ln(S));
      }
      if (tid < HD) {
        float cx = __fdiv_rn(px, S), cy = __fdiv_rn(py, S);
        float ctxd = fmaf(C0a[tid], cx, fmaf(C1a[tid], cy, C2a[tid]));
        float val = __fadd_rn(__fadd_rn(ctxd, wc2v[tid]), bca[tid]);
        hstm[tid] = fast_tanh(val);
      }
      niR = ni;
    }
    __syncthreads();                               // b4
  }
}

extern "C" void kernel_launch(void* const* d_in, const int* in_sizes, int n_in,
                              void* d_out, int out_size, void* d_ws, size_t ws_size,
                              hipStream_t stream) {
  (void)in_sizes; (void)n_in; (void)out_size; (void)d_ws; (void)ws_size;
  (void)hipFuncSetAttribute((const void*)evrp_kernel,
                            hipFuncAttributeMaxDynamicSharedMemorySize,
                            SEQN * HD * 4);
  evrp_kernel<<<dim3(BSZ), dim3(512), SEQN * HD * 4, stream>>>(
      (const float*)d_in[0],  (const float*)d_in[1],  (const float*)d_in[2],
      (const float*)d_in[3],  (const float*)d_in[4],  (const float*)d_in[5],
      (const float*)d_in[6],  (const float*)d_in[7],  (const float*)d_in[8],
      (const float*)d_in[9],  (const float*)d_in[10], (const float*)d_in[11],
      (const float*)d_in[12], (const float*)d_in[13], (const float*)d_in[14],
      (const int*)d_in[15],   (float*)d_out);
}

// Round 8
// 853.163 us; speedup vs baseline: 2.9881x; 1.0904x over previous
//
#include <hip/hip_runtime.h>
#include <cmath>

// EVRP solver rollout — one block per batch element, 128-step decode on-device.
// PRNG: JAX threefry2x32 partitionable scheme (verified). Discrete state path
// (fuel/time/demand/mask) is bit-exact vs jnp f32; logit path is analog.
// R8: DPP shuffles (quad_perm/ror) replace DS shuffles; packed FG combine;
// global load/store issue moved post-barrier to hide latency under AB.
#define BSZ 256
#define SEQN 256
#define HD 128
#define NEGV -1000000000.0f
#define TINYF 1.17549435e-38f
#define LOG2E 1.4426950408889634f
#define LN2F 0.6931471805599453f

typedef float v2f __attribute__((ext_vector_type(2)));

static __device__ __forceinline__ v2f mk2(float a, float b) {
  v2f r; r.x = a; r.y = b; return r;
}
static __device__ __forceinline__ v2f fma2(v2f a, v2f b, v2f c) {
  return __builtin_elementwise_fma(a, b, c);
}

// DPP lane ops (VALU pipe — not LDS). quad_perm 0xB1=xor1, 0x4E=xor2, 0x1B=xor3.
#define DPPF(x, c) __int_as_float(__builtin_amdgcn_update_dpp(0, __float_as_int(x), (c), 0xF, 0xF, true))
#define DPPI(x, c) __builtin_amdgcn_update_dpp(0, (x), (c), 0xF, 0xF, true)
#define SWZF(x, p) __int_as_float(__builtin_amdgcn_ds_swizzle(__float_as_int(x), (p)))

static __device__ __forceinline__ void tf2x32(unsigned k0, unsigned k1,
                                              unsigned x0, unsigned x1,
                                              unsigned &o0, unsigned &o1) {
  unsigned ks2 = k0 ^ k1 ^ 0x1BD11BDAu;
#define TFR(r) { x0 += x1; x1 = (x1 << (r)) | (x1 >> (32 - (r))); x1 ^= x0; }
  x0 += k0; x1 += k1;
  TFR(13) TFR(15) TFR(26) TFR(6)
  x0 += k1; x1 += ks2 + 1u;
  TFR(17) TFR(29) TFR(16) TFR(24)
  x0 += ks2; x1 += k0 + 2u;
  TFR(13) TFR(15) TFR(26) TFR(6)
  x0 += k0; x1 += k1 + 3u;
  TFR(17) TFR(29) TFR(16) TFR(24)
  x0 += k1; x1 += ks2 + 4u;
  TFR(13) TFR(15) TFR(26) TFR(6)
  x0 += ks2; x1 += k0 + 5u;
#undef TFR
  o0 = x0; o1 = x1;
}

static __device__ __forceinline__ float fast_tanh(float x) {
  float y = __fmul_rn(x, 2.885390081777927f);                 // 2*log2(e)*x
  float ay = __int_as_float(__float_as_int(y) | 0x80000000u); // -|y|
  float q = __builtin_amdgcn_exp2f(ay);
  float r = __fmul_rn(__fsub_rn(1.0f, q),
                      __builtin_amdgcn_rcpf(__fadd_rn(1.0f, q)));
  unsigned sgn = (unsigned)__float_as_int(x) & 0x80000000u;
  return __int_as_float(__float_as_int(r) | sgn);
}

static __device__ __forceinline__ float fast_sig(float x) {
  float q = __builtin_amdgcn_exp2f(__fmul_rn(x, -LOG2E));
  return __builtin_amdgcn_rcpf(__fadd_rn(1.0f, q));
}

static __device__ __forceinline__ float fast_ln(float x) {
  return __fmul_rn(__builtin_amdgcn_logf(x), LN2F);
}

// tanh(x) = (s-1)/(s+1), s = e^{2x} clamped — packable, finite for finite x.
static __device__ __forceinline__ v2f tanh2(v2f x) {
  v2f y = x * mk2(2.885390081777927f, 2.885390081777927f);
  y = __builtin_elementwise_min(y, mk2(48.0f, 48.0f));
  v2f s; s.x = __builtin_amdgcn_exp2f(y.x); s.y = __builtin_amdgcn_exp2f(y.y);
  v2f n = s + mk2(-1.0f, -1.0f);
  v2f d = s + mk2(1.0f, 1.0f);
  v2f r; r.x = __builtin_amdgcn_rcpf(d.x); r.y = __builtin_amdgcn_rcpf(d.y);
  return n * r;
}

__global__ __launch_bounds__(512, 2) void evrp_kernel(
    const float* __restrict__ statc, const float* __restrict__ dyn,
    const float* __restrict__ dist,  const float* __restrict__ W_s,
    const float* __restrict__ b_s,   const float* __restrict__ W_d,
    const float* __restrict__ b_d,   const float* __restrict__ W_i,
    const float* __restrict__ W_h,   const float* __restrict__ b_i,
    const float* __restrict__ b_h,   const float* __restrict__ W_att,
    const float* __restrict__ v_att, const float* __restrict__ W_c,
    const float* __restrict__ b_c,   const int* __restrict__ steps_p,
    float* __restrict__ out) {
  const int b = blockIdx.x;
  const int tid = threadIdx.x;
  const int T = steps_p[0];
  const int lane = tid & 63;
  const int wv = tid >> 6;
  const int s = tid >> 1, hf = tid & 1;      // E/FG mapping
  const int cq = tid >> 2, g = tid & 3;      // AB/C mapping

  extern __shared__ __align__(16) float4 Pdyn[];   // [16 chunks][512 sl] = 128KB

  __shared__ __align__(16) float  B0a[HD], B1a[HD], A2a[HD];
  __shared__ __align__(16) float  Ct[HD], Vt[HD];
  __shared__ __align__(16) float  hstm[HD], hlm[HD], wc2v[HD];
  __shared__ __align__(16) float  A0a[HD], A1a[HD], D0a[HD];
  __shared__ __align__(16) float  C0a[HD], C1a[HD], C2a[HD], bca[HD];
  __shared__ __align__(16) float2 xy2[SEQN];
  __shared__ __align__(16) float  drowX[SEQN];
  __shared__ __align__(16) unsigned kAs[256], kBs[256];
  __shared__ __align__(16) float ws0[HD], ws1[HD], bsv[HD];
  __shared__ __align__(16) float wd0[HD], wd1[HD], wd2[HD], bdv[HD];
  __shared__ __align__(16) float2 wredA[8];   // {av, (float)ai}
  __shared__ __align__(16) float4 wredB[8];   // {S, px, py, -}

  const float* distb = dist + (size_t)b * SEQN * SEQN;

  // ---------------- prologue: loads ----------------
  if (tid < HD) {
    ws0[tid] = W_s[2 * tid]; ws1[tid] = W_s[2 * tid + 1]; bsv[tid] = b_s[tid];
    wd0[tid] = W_d[3 * tid]; wd1[tid] = W_d[3 * tid + 1]; wd2[tid] = W_d[3 * tid + 2];
    bdv[tid] = b_d[tid]; bca[tid] = b_c[tid];
    hstm[tid] = 0.0f;
  }
  float xreg = statc[b * 2 * SEQN + s];
  float yreg = statc[b * 2 * SEQN + SEQN + s];
  float demreg = dyn[b * 3 * SEQN + 2 * SEQN + s];
  float d2dR = distb[(size_t)s * SEQN];
  float dbaR;
  {
    float d10 = distb[1 * SEQN + 0], d20 = distb[2 * SEQN + 0], d30 = distb[3 * SEQN + 0];
    float d1s = distb[1 * SEQN + s], d2s = distb[2 * SEQN + s], d3s = distb[3 * SEQN + s];
    float m = fminf(fminf(__fadd_rn(d10, d1s), __fadd_rn(d20, d2s)), __fadd_rn(d30, d3s));
    dbaR = (s == 0) ? 0.0f : m;
  }
  float dnextR = distb[s];       // row 0 — fills drowX at E_0
  if (hf == 0) xy2[s] = make_float2(xreg, yreg);
  float fuelR = dyn[b * 3 * SEQN + 0];
  float timeR = dyn[b * 3 * SEQN + SEQN + 0];
  float cstR = 0.0f;
  int niR = 0;
  for (int tt = tid; tt < 256; tt += 512) {
    unsigned a0, a1; tf2x32(0u, 1u, 0u, (unsigned)tt, a0, a1);
    kAs[tt] = a0; kBs[tt] = a1;
  }
  __syncthreads();

  // ---------------- prologue: folds + register weights ----------------
  if (tid < HD) {
    int k = tid;
    const float* row = W_att + (size_t)k * 384;
    float B0 = 0, B1 = 0, B2 = 0, A0 = 0, A1 = 0, A2 = 0, A3 = 0;
    for (int c = 0; c < HD; ++c) {
      float w1 = row[c], w2 = row[128 + c];
      B0 = fmaf(w1, ws0[c], B0); B1 = fmaf(w1, ws1[c], B1); B2 = fmaf(w1, bsv[c], B2);
      A0 = fmaf(w2, wd0[c], A0); A1 = fmaf(w2, wd1[c], A1);
      A2 = fmaf(w2, wd2[c], A2); A3 = fmaf(w2, bdv[c], A3);
    }
    B0a[k] = B0; B1a[k] = B1; A2a[k] = A2; Vt[k] = v_att[k];
    A0a[k] = A0; A1a[k] = A1; D0a[k] = __fadd_rn(B2, A3);
  } else if (tid < 2 * HD) {
    int o = tid - HD;
    const float* row = W_c + (size_t)o * 256;
    float C0 = 0, C1 = 0, C2 = 0;
    for (int c = 0; c < HD; ++c) {
      float w = row[c];
      C0 = fmaf(w, ws0[c], C0); C1 = fmaf(w, ws1[c], C1); C2 = fmaf(w, bsv[c], C2);
    }
    C0a[o] = C0; C1a[o] = C1; C2a[o] = C2;
  }
  float gp0 = 0, gp1 = 0, gp2 = 0, gpw;
  {
    int j = g * HD + cq;
    const float* row = W_i + (size_t)j * HD;
    for (int c = 0; c < HD; ++c) {
      float w = row[c];
      gp0 = fmaf(w, ws0[c], gp0); gp1 = fmaf(w, ws1[c], gp1); gp2 = fmaf(w, bsv[c], gp2);
    }
    gpw = __fadd_rn(b_i[j], b_h[j]);
  }
  // register-resident weights as v2f pairs — loaded once, then made OPAQUE
  // (empty asm, value-preserving) so the allocator cannot stream them.
  v2f whreg2[HD / 2];
  {
    int j = g * HD + cq;
#pragma unroll
    for (int c2 = 0; c2 < HD / 2; ++c2)
      whreg2[c2] = *(const v2f*)(&W_h[(size_t)j * HD + 2 * c2]);
  }
  v2f wah2[16], wc22[16];
#pragma unroll
  for (int i = 0; i < 16; ++i) {
    wah2[i] = *(const v2f*)(&W_att[(size_t)cq * 384 + 256 + g * 32 + 2 * i]);
    wc22[i] = *(const v2f*)(&W_c[(size_t)cq * 256 + HD + g * 32 + 2 * i]);
  }
#pragma unroll
  for (int c = 0; c < HD / 2; c += 2)
    asm volatile("" : "+v"(whreg2[c]), "+v"(whreg2[c + 1]));
#pragma unroll
  for (int i = 0; i < 16; i += 2) {
    asm volatile("" : "+v"(wah2[i]), "+v"(wah2[i + 1]));
    asm volatile("" : "+v"(wc22[i]), "+v"(wc22[i + 1]));
  }
  __syncthreads();

  // ---------------- prologue: fill P[s][k] (constant over rollout) ----------
  for (int idx = tid; idx < SEQN * HD; idx += 512) {
    int ss = idx >> 7, k = idx & 127;
    float2 pxy = xy2[ss];
    float dm = dyn[b * 3 * SEQN + 2 * SEQN + ss];
    float pv = fmaf(B0a[k], pxy.x, fmaf(B1a[k], pxy.y, __fmul_rn(A2a[k], dm)));
    ((float*)Pdyn)[(((k >> 2) & 15) << 11) + ((ss * 2 + (k >> 6)) << 2) + (k & 3)] = pv;
  }
  __syncthreads();

  float decxR = xy2[0].x, decyR = xy2[0].y;

  float* out_probs = out;
  float* out_tours = out + (size_t)BSZ * T * SEQN;
  float* out_logps = out_tours + (size_t)BSZ * T;

  const float4* Pp = Pdyn + (s * 2 + hf);   // + chunk*512
  const float* CtH = Ct + hf * 64;
  const float* VtH = Vt + hf * 64;

  float prevPr = 0.0f, prevLp = 0.0f;
  int prevNi = 0;

  // ---------------- decode loop (4 barriers/step) ----------------
  for (int t = 0; t < T; ++t) {
    // ---- top: issue prev-step stores + this step's distance-row gather ----
    // (drains at b1, hidden under AB — not at b4 like before)
    if (t > 0) {
      if (hf == 0) out_probs[((size_t)b * T + (t - 1)) * SEQN + s] = prevPr;
      if (s == prevNi && hf == 0) {
        out_tours[(size_t)b * T + (t - 1)] = (float)prevNi;
        out_logps[(size_t)b * T + (t - 1)] = prevLp;
      }
      dnextR = distb[(size_t)niR * SEQN + s];
    }
    // ---- AB: gates + LSTM via quad DPP exchange ---- [all 512; (cq,g)]
    {
      v2f mA = mk2(0.f, 0.f), mB = mk2(0.f, 0.f);
      const float4* h4 = (const float4*)hstm;
#pragma unroll
      for (int c4 = 0; c4 < HD / 4; ++c4) {
        float4 hh = h4[c4];
        mA = fma2(whreg2[2 * c4],     mk2(hh.x, hh.y), mA);
        mB = fma2(whreg2[2 * c4 + 1], mk2(hh.z, hh.w), mB);
      }
      float md = fmaf(gp0, decxR, fmaf(gp1, decyR, gp2));
      float mh = __fadd_rn(__fadd_rn(mA.x, mA.y), __fadd_rn(mB.x, mB.y));
      float V = __fadd_rn(__fadd_rn(md, mh), gpw);
      float sg = fast_sig(V), th = fast_tanh(V);
      float q = (g == 2) ? th : sg;
      float u1 = DPPF(q, 0xB1);
      float u2 = DPPF(q, 0x4E);
      float u3 = DPPF(q, 0x1B);
      float qi = (g == 0) ? q  : (g == 1) ? u1 : (g == 2) ? u2 : u3;
      float qf = (g == 0) ? u1 : (g == 1) ? q  : (g == 2) ? u3 : u2;
      float qg = (g == 0) ? u2 : (g == 1) ? u3 : (g == 2) ? q  : u1;
      float qo = (g == 0) ? u3 : (g == 1) ? u2 : (g == 2) ? u1 : q;
      float cn = __fadd_rn(__fmul_rn(qf, cstR), __fmul_rn(qi, qg));
      cstR = cn;
      float hv = __fmul_rn(qo, fast_tanh(cn));
      if (g == 0) hlm[(cq & 96) | ((cq & 31) ^ ((cq >> 5) << 3))] = hv;
    }
    __syncthreads();                               // b1
    // ---- C: W_att_h@h, W_c2@h; quad DPP reduce; write Ct ---- [(cq,g)]
    {
      v2f pwA = mk2(0.f, 0.f), pwB = mk2(0.f, 0.f);
      v2f pcA = mk2(0.f, 0.f), pcB = mk2(0.f, 0.f);
      const float4* hl4 = (const float4*)hlm;
#pragma unroll
      for (int l4 = 0; l4 < 8; ++l4) {
        float4 hh = hl4[(g << 3) + (l4 ^ (g << 1))];   // XOR-swizzled, conflict-free
        v2f hA = mk2(hh.x, hh.y), hB = mk2(hh.z, hh.w);
        pwA = fma2(wah2[2 * l4],     hA, pwA);
        pwB = fma2(wah2[2 * l4 + 1], hB, pwB);
        pcA = fma2(wc22[2 * l4],     hA, pcA);
        pcB = fma2(wc22[2 * l4 + 1], hB, pcB);
      }
      float pw = __fadd_rn(__fadd_rn(pwA.x, pwA.y), __fadd_rn(pwB.x, pwB.y));
      float pc = __fadd_rn(__fadd_rn(pcA.x, pcA.y), __fadd_rn(pcB.x, pcB.y));
      pw = __fadd_rn(pw, DPPF(pw, 0xB1));
      pc = __fadd_rn(pc, DPPF(pc, 0xB1));
      pw = __fadd_rn(pw, DPPF(pw, 0x4E));
      pc = __fadd_rn(pc, DPPF(pc, 0x4E));
      if (g == 0) {
        wc2v[cq] = pc;
        Ct[cq] = fmaf(A0a[cq], fuelR, fmaf(A1a[cq], timeR, __fadd_rn(D0a[cq], pw)));
      }
    }
    __syncthreads();                               // b2
    // ---- E: mask, drow fill, tanh loop, gumbel, DPP-reduce ---- [(s,hf)]
    float pe, lg;
    if (hf == 0) drowX[s] = dnextR;   // row of node niR (prev step's pick)
    bool mk;
    if (t == 0) mk = true;
    else {
      bool fok = fuelR >= __fmul_rn(0.2f, __fadd_rn(dnextR, dbaR));
      bool tok = timeR >= __fdiv_rn(__fadd_rn(dnextR, d2dR), 60.0f);
      bool cust = (demreg > 0.0f) && fok && tok;
      mk = (s <= 3) ? (s != niR) : cust;
      if (s == 0) mk = true;
    }
    {
      unsigned rb;
      { unsigned o0, o1; tf2x32(kAs[t], kBs[t], 0u, (unsigned)(b * SEQN + s), o0, o1); rb = o0 ^ o1; }
      float f = __uint_as_float((rb >> 9) | 0x3f800000u) - 1.0f;
      float u = fmaxf(TINYF, __fadd_rn(f, TINYF));
      float gmb = -fast_ln(-fast_ln(u));
      v2f acc2 = mk2(0.f, 0.f);
#pragma unroll
      for (int i = 0; i < 16; ++i) {
        float4 pv = Pp[i << 9];
        float4 ct = *(const float4*)(CtH + 4 * i);
        float4 vv = *(const float4*)(VtH + 4 * i);
        v2f a0 = mk2(pv.x, pv.y) + mk2(ct.x, ct.y);
        acc2 = fma2(mk2(vv.x, vv.y), tanh2(a0), acc2);
        v2f a1 = mk2(pv.z, pv.w) + mk2(ct.z, ct.w);
        acc2 = fma2(mk2(vv.z, vv.w), tanh2(a1), acc2);
      }
      float acc = __fadd_rn(acc2.x, acc2.y);
      float e = __fadd_rn(acc, DPPF(acc, 0xB1));   // exact xor1 (pair lanes)
      lg = mk ? e : NEGV;
      pe = __builtin_amdgcn_exp2f(__fmul_rn(lg, LOG2E));
      float sc = __fadd_rn(gmb, lg);
      float av = sc; int ai = s;
      float S = pe, px = __fmul_rn(pe, xreg), py = __fmul_rn(pe, yreg);
      // DPP rotation reduce: xor2, ror4, ror8 (VALU); then xor16 swizzle, xor32.
      // Coverage per 16-lane row: {p,p^1} ∪ +2 ∪ +4 → all 8 nodes exactly once.
      {
        float ov = DPPF(av, 0x4E); int oi = DPPI(ai, 0x4E);
        if (ov > av || (ov == av && oi < ai)) { av = ov; ai = oi; }
        S  = __fadd_rn(S,  DPPF(S,  0x4E));
        px = __fadd_rn(px, DPPF(px, 0x4E));
        py = __fadd_rn(py, DPPF(py, 0x4E));
      }
      {
        float ov = DPPF(av, 0x124); int oi = DPPI(ai, 0x124);
        if (ov > av || (ov == av && oi < ai)) { av = ov; ai = oi; }
        S  = __fadd_rn(S,  DPPF(S,  0x124));
        px = __fadd_rn(px, DPPF(px, 0x124));
        py = __fadd_rn(py, DPPF(py, 0x124));
      }
      {
        float ov = DPPF(av, 0x128); int oi = DPPI(ai, 0x128);
        if (ov > av || (ov == av && oi < ai)) { av = ov; ai = oi; }
        S  = __fadd_rn(S,  DPPF(S,  0x128));
        px = __fadd_rn(px, DPPF(px, 0x128));
        py = __fadd_rn(py, DPPF(py, 0x128));
      }
      {
        float ov = SWZF(av, 0x401F); int oi = __builtin_amdgcn_ds_swizzle(ai, 0x401F);
        if (ov > av || (ov == av && oi < ai)) { av = ov; ai = oi; }
        S  = __fadd_rn(S,  SWZF(S,  0x401F));
        px = __fadd_rn(px, SWZF(px, 0x401F));
        py = __fadd_rn(py, SWZF(py, 0x401F));
      }
      {
        float ov = __shfl_xor(av, 32, 64); int oi = __shfl_xor(ai, 32, 64);
        if (ov > av || (ov == av && oi < ai)) { av = ov; ai = oi; }
        S  = __fadd_rn(S,  __shfl_xor(S,  32, 64));
        px = __fadd_rn(px, __shfl_xor(px, 32, 64));
        py = __fadd_rn(py, __shfl_xor(py, 32, 64));
      }
      if (lane == 0) {
        wredA[wv] = make_float2(av, (float)ai);
        wredB[wv] = make_float4(S, px, py, 0.0f);
      }
    }
    __syncthreads();                               // b3
    // ---- FG: packed final combine, state update, h_new ----
    {
      float2 a0 = wredA[0];
      float bv = a0.x; int bi = (int)a0.y;
#pragma unroll
      for (int w = 1; w < 8; ++w) {
        float2 aw = wredA[w];
        if (aw.x > bv) { bv = aw.x; bi = (int)aw.y; }
      }
      int ni = bi;
      float4 b0 = wredB[0];
      float S = b0.x, px = b0.y, py = b0.z;
#pragma unroll
      for (int w = 1; w < 8; ++w) {
        float4 bw = wredB[w];
        S = __fadd_rn(S, bw.x); px = __fadd_rn(px, bw.y); py = __fadd_rn(py, bw.z);
      }
      float dis = drowX[ni];
      float fl = __fsub_rn(fuelR, __fmul_rn(0.2f, dis));
      float tm = __fsub_rn(timeR, __fdiv_rn(dis, 60.0f));
      if (ni <= 3) fl = 60.0f;
      if (ni == 0) tm = 11.0f;
      fuelR = fl; timeR = tm;
      if (s == ni && ni > 3) demreg = 0.0f;
      float2 dxy = xy2[ni];
      decxR = dxy.x; decyR = dxy.y;
      prevPr = __fdiv_rn(pe, S);
      prevLp = __fsub_rn(lg, fast_ln(S));
      prevNi = ni;
      if (tid < HD) {
        float cx = __fdiv_rn(px, S), cy = __fdiv_rn(py, S);
        float ctxd = fmaf(C0a[tid], cx, fmaf(C1a[tid], cy, C2a[tid]));
        float val = __fadd_rn(__fadd_rn(ctxd, wc2v[tid]), bca[tid]);
        hstm[tid] = fast_tanh(val);
      }
      niR = ni;
    }
    __syncthreads();                               // b4
  }
  // final step's outputs
  if (hf == 0) out_probs[((size_t)b * T + (T - 1)) * SEQN + s] = prevPr;
  if (s == prevNi && hf == 0) {
    out_tours[(size_t)b * T + (T - 1)] = (float)prevNi;
    out_logps[(size_t)b * T + (T - 1)] = prevLp;
  }
}

extern "C" void kernel_launch(void* const* d_in, const int* in_sizes, int n_in,
                              void* d_out, int out_size, void* d_ws, size_t ws_size,
                              hipStream_t stream) {
  (void)in_sizes; (void)n_in; (void)out_size; (void)d_ws; (void)ws_size;
  (void)hipFuncSetAttribute((const void*)evrp_kernel,
                            hipFuncAttributeMaxDynamicSharedMemorySize,
                            SEQN * HD * 4);
  evrp_kernel<<<dim3(BSZ), dim3(512), SEQN * HD * 4, stream>>>(
      (const float*)d_in[0],  (const float*)d_in[1],  (const float*)d_in[2],
      (const float*)d_in[3],  (const float*)d_in[4],  (const float*)d_in[5],
      (const float*)d_in[6],  (const float*)d_in[7],  (const float*)d_in[8],
      (const float*)d_in[9],  (const float*)d_in[10], (const float*)d_in[11],
      (const float*)d_in[12], (const float*)d_in[13], (const float*)d_in[14],
      (const int*)d_in[15],   (float*)d_out);
}

// Round 9
// 747.773 us; speedup vs baseline: 3.4093x; 1.1409x over previous
//
#include <hip/hip_runtime.h>
#include <cmath>

// EVRP solver rollout — one block per batch element, 128-step decode on-device.
// PRNG: JAX threefry2x32 partitionable scheme (verified). Discrete state path
// (fuel/time/demand/mask) is bit-exact vs jnp f32; logit path is analog.
// R9: exp-split attention — tanh(P+C) = 1 - 2/(sP*sC+1), sP=exp2(2l2e*P)
// precomputed static in LDS, sC=exp2(2l2e*C) once per k per step. E inner
// chain: mul,add,rcp,fma (no exp). 4 independent acc chains in AB and E.
#define BSZ 256
#define SEQN 256
#define HD 128
#define NEGV -1000000000.0f
#define TINYF 1.17549435e-38f
#define LOG2E 1.4426950408889634f
#define LN2F 0.6931471805599453f
#define K2L 2.885390081777927f

typedef float v2f __attribute__((ext_vector_type(2)));

static __device__ __forceinline__ v2f mk2(float a, float b) {
  v2f r; r.x = a; r.y = b; return r;
}
static __device__ __forceinline__ v2f fma2(v2f a, v2f b, v2f c) {
  return __builtin_elementwise_fma(a, b, c);
}

// DPP lane ops (VALU pipe — not LDS). quad_perm 0xB1=xor1, 0x4E=xor2, 0x1B=xor3.
#define DPPF(x, c) __int_as_float(__builtin_amdgcn_update_dpp(0, __float_as_int(x), (c), 0xF, 0xF, true))
#define DPPI(x, c) __builtin_amdgcn_update_dpp(0, (x), (c), 0xF, 0xF, true)
#define SWZF(x, p) __int_as_float(__builtin_amdgcn_ds_swizzle(__float_as_int(x), (p)))

static __device__ __forceinline__ void tf2x32(unsigned k0, unsigned k1,
                                              unsigned x0, unsigned x1,
                                              unsigned &o0, unsigned &o1) {
  unsigned ks2 = k0 ^ k1 ^ 0x1BD11BDAu;
#define TFR(r) { x0 += x1; x1 = (x1 << (r)) | (x1 >> (32 - (r))); x1 ^= x0; }
  x0 += k0; x1 += k1;
  TFR(13) TFR(15) TFR(26) TFR(6)
  x0 += k1; x1 += ks2 + 1u;
  TFR(17) TFR(29) TFR(16) TFR(24)
  x0 += ks2; x1 += k0 + 2u;
  TFR(13) TFR(15) TFR(26) TFR(6)
  x0 += k0; x1 += k1 + 3u;
  TFR(17) TFR(29) TFR(16) TFR(24)
  x0 += k1; x1 += ks2 + 4u;
  TFR(13) TFR(15) TFR(26) TFR(6)
  x0 += ks2; x1 += k0 + 5u;
#undef TFR
  o0 = x0; o1 = x1;
}

static __device__ __forceinline__ float fast_tanh(float x) {
  float y = __fmul_rn(x, K2L);
  float ay = __int_as_float(__float_as_int(y) | 0x80000000u); // -|y|
  float q = __builtin_amdgcn_exp2f(ay);
  float r = __fmul_rn(__fsub_rn(1.0f, q),
                      __builtin_amdgcn_rcpf(__fadd_rn(1.0f, q)));
  unsigned sgn = (unsigned)__float_as_int(x) & 0x80000000u;
  return __int_as_float(__float_as_int(r) | sgn);
}

static __device__ __forceinline__ float fast_sig(float x) {
  float q = __builtin_amdgcn_exp2f(__fmul_rn(x, -LOG2E));
  return __builtin_amdgcn_rcpf(__fadd_rn(1.0f, q));
}

static __device__ __forceinline__ float fast_ln(float x) {
  return __fmul_rn(__builtin_amdgcn_logf(x), LN2F);
}

__global__ __launch_bounds__(512, 2) void evrp_kernel(
    const float* __restrict__ statc, const float* __restrict__ dyn,
    const float* __restrict__ dist,  const float* __restrict__ W_s,
    const float* __restrict__ b_s,   const float* __restrict__ W_d,
    const float* __restrict__ b_d,   const float* __restrict__ W_i,
    const float* __restrict__ W_h,   const float* __restrict__ b_i,
    const float* __restrict__ b_h,   const float* __restrict__ W_att,
    const float* __restrict__ v_att, const float* __restrict__ W_c,
    const float* __restrict__ b_c,   const int* __restrict__ steps_p,
    float* __restrict__ out) {
  const int b = blockIdx.x;
  const int tid = threadIdx.x;
  const int T = steps_p[0];
  const int lane = tid & 63;
  const int wv = tid >> 6;
  const int s = tid >> 1, hf = tid & 1;      // E/FG mapping
  const int cq = tid >> 2, g = tid & 3;      // AB/C mapping

  extern __shared__ __align__(16) float4 Pdyn[];   // sP: [16 chunks][512] = 128KB

  __shared__ __align__(16) float  B0a[HD], B1a[HD], A2a[HD];
  __shared__ __align__(16) float  Ct[HD], Vt[HD];   // Ct holds sC per step
  __shared__ __align__(16) float  hstm[HD], hlm[HD], wc2v[HD];
  __shared__ __align__(16) float  A0a[HD], A1a[HD], D0a[HD];
  __shared__ __align__(16) float  C0a[HD], C1a[HD], C2a[HD], bca[HD];
  __shared__ __align__(16) float2 xy2[SEQN];
  __shared__ __align__(16) float  drowX[SEQN];
  __shared__ __align__(16) unsigned kAs[256], kBs[256];
  __shared__ __align__(16) float ws0[HD], ws1[HD], bsv[HD];
  __shared__ __align__(16) float wd0[HD], wd1[HD], wd2[HD], bdv[HD];
  __shared__ __align__(16) float2 wredA[8];   // {av, (float)ai}
  __shared__ __align__(16) float4 wredB[8];   // {S, px, py, -}

  const float* distb = dist + (size_t)b * SEQN * SEQN;

  // ---------------- prologue: loads ----------------
  if (tid < HD) {
    ws0[tid] = W_s[2 * tid]; ws1[tid] = W_s[2 * tid + 1]; bsv[tid] = b_s[tid];
    wd0[tid] = W_d[3 * tid]; wd1[tid] = W_d[3 * tid + 1]; wd2[tid] = W_d[3 * tid + 2];
    bdv[tid] = b_d[tid]; bca[tid] = b_c[tid];
    hstm[tid] = 0.0f;
  }
  float xreg = statc[b * 2 * SEQN + s];
  float yreg = statc[b * 2 * SEQN + SEQN + s];
  float demreg = dyn[b * 3 * SEQN + 2 * SEQN + s];
  float d2dR = distb[(size_t)s * SEQN];
  float dbaR;
  {
    float d10 = distb[1 * SEQN + 0], d20 = distb[2 * SEQN + 0], d30 = distb[3 * SEQN + 0];
    float d1s = distb[1 * SEQN + s], d2s = distb[2 * SEQN + s], d3s = distb[3 * SEQN + s];
    float m = fminf(fminf(__fadd_rn(d10, d1s), __fadd_rn(d20, d2s)), __fadd_rn(d30, d3s));
    dbaR = (s == 0) ? 0.0f : m;
  }
  float dnextR = distb[s];       // row 0 — fills drowX at E_0
  if (hf == 0) xy2[s] = make_float2(xreg, yreg);
  float fuelR = dyn[b * 3 * SEQN + 0];
  float timeR = dyn[b * 3 * SEQN + SEQN + 0];
  float cstR = 0.0f;
  int niR = 0;
  for (int tt = tid; tt < 256; tt += 512) {
    unsigned a0, a1; tf2x32(0u, 1u, 0u, (unsigned)tt, a0, a1);
    kAs[tt] = a0; kBs[tt] = a1;
  }
  __syncthreads();

  // ---------------- prologue: folds + register weights ----------------
  if (tid < HD) {
    int k = tid;
    const float* row = W_att + (size_t)k * 384;
    float B0 = 0, B1 = 0, B2 = 0, A0 = 0, A1 = 0, A2 = 0, A3 = 0;
    for (int c = 0; c < HD; ++c) {
      float w1 = row[c], w2 = row[128 + c];
      B0 = fmaf(w1, ws0[c], B0); B1 = fmaf(w1, ws1[c], B1); B2 = fmaf(w1, bsv[c], B2);
      A0 = fmaf(w2, wd0[c], A0); A1 = fmaf(w2, wd1[c], A1);
      A2 = fmaf(w2, wd2[c], A2); A3 = fmaf(w2, bdv[c], A3);
    }
    B0a[k] = B0; B1a[k] = B1; A2a[k] = A2; Vt[k] = v_att[k];
    A0a[k] = A0; A1a[k] = A1; D0a[k] = __fadd_rn(B2, A3);
  } else if (tid < 2 * HD) {
    int o = tid - HD;
    const float* row = W_c + (size_t)o * 256;
    float C0 = 0, C1 = 0, C2 = 0;
    for (int c = 0; c < HD; ++c) {
      float w = row[c];
      C0 = fmaf(w, ws0[c], C0); C1 = fmaf(w, ws1[c], C1); C2 = fmaf(w, bsv[c], C2);
    }
    C0a[o] = C0; C1a[o] = C1; C2a[o] = C2;
  }
  float gp0 = 0, gp1 = 0, gp2 = 0, gpw;
  {
    int j = g * HD + cq;
    const float* row = W_i + (size_t)j * HD;
    for (int c = 0; c < HD; ++c) {
      float w = row[c];
      gp0 = fmaf(w, ws0[c], gp0); gp1 = fmaf(w, ws1[c], gp1); gp2 = fmaf(w, bsv[c], gp2);
    }
    gpw = __fadd_rn(b_i[j], b_h[j]);
  }
  // register-resident weights as v2f pairs — loaded once, then made OPAQUE
  // (empty asm, value-preserving) so the allocator cannot stream them.
  v2f whreg2[HD / 2];
  {
    int j = g * HD + cq;
#pragma unroll
    for (int c2 = 0; c2 < HD / 2; ++c2)
      whreg2[c2] = *(const v2f*)(&W_h[(size_t)j * HD + 2 * c2]);
  }
  v2f wah2[16], wc22[16];
#pragma unroll
  for (int i = 0; i < 16; ++i) {
    wah2[i] = *(const v2f*)(&W_att[(size_t)cq * 384 + 256 + g * 32 + 2 * i]);
    wc22[i] = *(const v2f*)(&W_c[(size_t)cq * 256 + HD + g * 32 + 2 * i]);
  }
#pragma unroll
  for (int c = 0; c < HD / 2; c += 2)
    asm volatile("" : "+v"(whreg2[c]), "+v"(whreg2[c + 1]));
#pragma unroll
  for (int i = 0; i < 16; i += 2) {
    asm volatile("" : "+v"(wah2[i]), "+v"(wah2[i + 1]));
    asm volatile("" : "+v"(wc22[i]), "+v"(wc22[i + 1]));
  }
  __syncthreads();

  // ---------------- prologue: fill sP[s][k] = exp2(K2L*P) (rollout-constant)
  for (int idx = tid; idx < SEQN * HD; idx += 512) {
    int ss = idx >> 7, k = idx & 127;
    float2 pxy = xy2[ss];
    float dm = dyn[b * 3 * SEQN + 2 * SEQN + ss];
    float pv = fmaf(B0a[k], pxy.x, fmaf(B1a[k], pxy.y, __fmul_rn(A2a[k], dm)));
    ((float*)Pdyn)[(((k >> 2) & 15) << 11) + ((ss * 2 + (k >> 6)) << 2) + (k & 3)] =
        __builtin_amdgcn_exp2f(__fmul_rn(pv, K2L));
  }
  // Vsum = sum of v_att (folds the "+1" of tanh identity); uniform all threads
  float Vsum = 0.0f;
#pragma unroll
  for (int i = 0; i < 32; ++i) {
    float4 v4 = ((const float4*)Vt)[i];
    Vsum = __fadd_rn(Vsum, __fadd_rn(__fadd_rn(v4.x, v4.y), __fadd_rn(v4.z, v4.w)));
  }
  __syncthreads();

  float decxR = xy2[0].x, decyR = xy2[0].y;

  float* out_probs = out;
  float* out_tours = out + (size_t)BSZ * T * SEQN;
  float* out_logps = out_tours + (size_t)BSZ * T;

  const float4* Pp = Pdyn + (s * 2 + hf);   // + chunk*512
  const float* CtH = Ct + hf * 64;
  const float* VtH = Vt + hf * 64;

  float prevPr = 0.0f, prevLp = 0.0f;
  int prevNi = 0;

  // ---------------- decode loop (4 barriers/step) ----------------
  for (int t = 0; t < T; ++t) {
    // ---- top: issue prev-step stores + this step's distance-row gather ----
    if (t > 0) {
      if (hf == 0) out_probs[((size_t)b * T + (t - 1)) * SEQN + s] = prevPr;
      if (s == prevNi && hf == 0) {
        out_tours[(size_t)b * T + (t - 1)] = (float)prevNi;
        out_logps[(size_t)b * T + (t - 1)] = prevLp;
      }
      dnextR = distb[(size_t)niR * SEQN + s];
    }
    // ---- AB: gates + LSTM via quad DPP exchange; 4 acc chains ---- [(cq,g)]
    {
      v2f mA0 = mk2(0.f, 0.f), mB0 = mk2(0.f, 0.f);
      v2f mA1 = mk2(0.f, 0.f), mB1 = mk2(0.f, 0.f);
      const float4* h4 = (const float4*)hstm;
#pragma unroll
      for (int c8 = 0; c8 < HD / 8; ++c8) {
        float4 h0 = h4[2 * c8], h1 = h4[2 * c8 + 1];
        mA0 = fma2(whreg2[4 * c8 + 0], mk2(h0.x, h0.y), mA0);
        mB0 = fma2(whreg2[4 * c8 + 1], mk2(h0.z, h0.w), mB0);
        mA1 = fma2(whreg2[4 * c8 + 2], mk2(h1.x, h1.y), mA1);
        mB1 = fma2(whreg2[4 * c8 + 3], mk2(h1.z, h1.w), mB1);
      }
      float md = fmaf(gp0, decxR, fmaf(gp1, decyR, gp2));
      float mh = __fadd_rn(
          __fadd_rn(__fadd_rn(mA0.x, mA0.y), __fadd_rn(mB0.x, mB0.y)),
          __fadd_rn(__fadd_rn(mA1.x, mA1.y), __fadd_rn(mB1.x, mB1.y)));
      float V = __fadd_rn(__fadd_rn(md, mh), gpw);
      float sg = fast_sig(V), th = fast_tanh(V);
      float q = (g == 2) ? th : sg;
      float u1 = DPPF(q, 0xB1);
      float u2 = DPPF(q, 0x4E);
      float u3 = DPPF(q, 0x1B);
      float qi = (g == 0) ? q  : (g == 1) ? u1 : (g == 2) ? u2 : u3;
      float qf = (g == 0) ? u1 : (g == 1) ? q  : (g == 2) ? u3 : u2;
      float qg = (g == 0) ? u2 : (g == 1) ? u3 : (g == 2) ? q  : u1;
      float qo = (g == 0) ? u3 : (g == 1) ? u2 : (g == 2) ? u1 : q;
      float cn = __fadd_rn(__fmul_rn(qf, cstR), __fmul_rn(qi, qg));
      cstR = cn;
      float hv = __fmul_rn(qo, fast_tanh(cn));
      if (g == 0) hlm[(cq & 96) | ((cq & 31) ^ ((cq >> 5) << 3))] = hv;
    }
    __syncthreads();                               // b1
    // ---- C: W_att_h@h, W_c2@h; quad DPP reduce; write sC into Ct ---- [(cq,g)]
    {
      v2f pwA = mk2(0.f, 0.f), pwB = mk2(0.f, 0.f);
      v2f pcA = mk2(0.f, 0.f), pcB = mk2(0.f, 0.f);
      const float4* hl4 = (const float4*)hlm;
#pragma unroll
      for (int l4 = 0; l4 < 8; ++l4) {
        float4 hh = hl4[(g << 3) + (l4 ^ (g << 1))];   // XOR-swizzled, conflict-free
        v2f hA = mk2(hh.x, hh.y), hB = mk2(hh.z, hh.w);
        pwA = fma2(wah2[2 * l4],     hA, pwA);
        pwB = fma2(wah2[2 * l4 + 1], hB, pwB);
        pcA = fma2(wc22[2 * l4],     hA, pcA);
        pcB = fma2(wc22[2 * l4 + 1], hB, pcB);
      }
      float pw = __fadd_rn(__fadd_rn(pwA.x, pwA.y), __fadd_rn(pwB.x, pwB.y));
      float pc = __fadd_rn(__fadd_rn(pcA.x, pcA.y), __fadd_rn(pcB.x, pcB.y));
      pw = __fadd_rn(pw, DPPF(pw, 0xB1));
      pc = __fadd_rn(pc, DPPF(pc, 0xB1));
      pw = __fadd_rn(pw, DPPF(pw, 0x4E));
      pc = __fadd_rn(pc, DPPF(pc, 0x4E));
      if (g == 0) {
        wc2v[cq] = pc;
        float Ck = fmaf(A0a[cq], fuelR, fmaf(A1a[cq], timeR, __fadd_rn(D0a[cq], pw)));
        Ct[cq] = __builtin_amdgcn_exp2f(__fmul_rn(Ck, K2L));   // sC
      }
    }
    __syncthreads();                               // b2
    // ---- E: mask, drow fill, rcp loop (no exp), gumbel, DPP-reduce ----
    float pe, lg;
    if (hf == 0) drowX[s] = dnextR;   // row of node niR (prev step's pick)
    bool mk;
    if (t == 0) mk = true;
    else {
      bool fok = fuelR >= __fmul_rn(0.2f, __fadd_rn(dnextR, dbaR));
      bool tok = timeR >= __fdiv_rn(__fadd_rn(dnextR, d2dR), 60.0f);
      bool cust = (demreg > 0.0f) && fok && tok;
      mk = (s <= 3) ? (s != niR) : cust;
      if (s == 0) mk = true;
    }
    {
      unsigned rb;
      { unsigned o0, o1; tf2x32(kAs[t], kBs[t], 0u, (unsigned)(b * SEQN + s), o0, o1); rb = o0 ^ o1; }
      float f = __uint_as_float((rb >> 9) | 0x3f800000u) - 1.0f;
      float u = fmaxf(TINYF, __fadd_rn(f, TINYF));
      float gmb = -fast_ln(-fast_ln(u));
      const v2f one2 = mk2(1.0f, 1.0f);
      v2f a0 = mk2(0.f, 0.f), a1 = mk2(0.f, 0.f);
      v2f a2 = mk2(0.f, 0.f), a3 = mk2(0.f, 0.f);
#pragma unroll
      for (int i = 0; i < 8; ++i) {
        // even group 2i → chains a0,a1; odd group 2i+1 → chains a2,a3
        float4 pv0 = Pp[(2 * i) << 9];
        float4 ct0 = *(const float4*)(CtH + 8 * i);
        float4 vv0 = *(const float4*)(VtH + 8 * i);
        v2f sA = mk2(pv0.x, pv0.y) * mk2(ct0.x, ct0.y) + one2;
        v2f sB = mk2(pv0.z, pv0.w) * mk2(ct0.z, ct0.w) + one2;
        v2f rA, rB;
        rA.x = __builtin_amdgcn_rcpf(sA.x); rA.y = __builtin_amdgcn_rcpf(sA.y);
        rB.x = __builtin_amdgcn_rcpf(sB.x); rB.y = __builtin_amdgcn_rcpf(sB.y);
        a0 = fma2(mk2(vv0.x, vv0.y), rA, a0);
        a1 = fma2(mk2(vv0.z, vv0.w), rB, a1);
        float4 pv1 = Pp[(2 * i + 1) << 9];
        float4 ct1 = *(const float4*)(CtH + 8 * i + 4);
        float4 vv1 = *(const float4*)(VtH + 8 * i + 4);
        v2f sC = mk2(pv1.x, pv1.y) * mk2(ct1.x, ct1.y) + one2;
        v2f sD = mk2(pv1.z, pv1.w) * mk2(ct1.z, ct1.w) + one2;
        v2f rC, rD;
        rC.x = __builtin_amdgcn_rcpf(sC.x); rC.y = __builtin_amdgcn_rcpf(sC.y);
        rD.x = __builtin_amdgcn_rcpf(sD.x); rD.y = __builtin_amdgcn_rcpf(sD.y);
        a2 = fma2(mk2(vv1.x, vv1.y), rC, a2);
        a3 = fma2(mk2(vv1.z, vv1.w), rD, a3);
      }
      v2f t01 = a0 + a1, t23 = a2 + a3;
      v2f tt = t01 + t23;
      float part = __fadd_rn(tt.x, tt.y);
      float tot = __fadd_rn(part, DPPF(part, 0xB1));   // both halves
      float e = fmaf(-2.0f, tot, Vsum);                // Σv·tanh = Σv − 2Σv/(s+1)
      lg = mk ? e : NEGV;
      pe = __builtin_amdgcn_exp2f(__fmul_rn(lg, LOG2E));
      float sc = __fadd_rn(gmb, lg);
      float av = sc; int ai = s;
      float S = pe, px = __fmul_rn(pe, xreg), py = __fmul_rn(pe, yreg);
      {
        float ov = DPPF(av, 0x4E); int oi = DPPI(ai, 0x4E);
        if (ov > av || (ov == av && oi < ai)) { av = ov; ai = oi; }
        S  = __fadd_rn(S,  DPPF(S,  0x4E));
        px = __fadd_rn(px, DPPF(px, 0x4E));
        py = __fadd_rn(py, DPPF(py, 0x4E));
      }
      {
        float ov = DPPF(av, 0x124); int oi = DPPI(ai, 0x124);
        if (ov > av || (ov == av && oi < ai)) { av = ov; ai = oi; }
        S  = __fadd_rn(S,  DPPF(S,  0x124));
        px = __fadd_rn(px, DPPF(px, 0x124));
        py = __fadd_rn(py, DPPF(py, 0x124));
      }
      {
        float ov = DPPF(av, 0x128); int oi = DPPI(ai, 0x128);
        if (ov > av || (ov == av && oi < ai)) { av = ov; ai = oi; }
        S  = __fadd_rn(S,  DPPF(S,  0x128));
        px = __fadd_rn(px, DPPF(px, 0x128));
        py = __fadd_rn(py, DPPF(py, 0x128));
      }
      {
        float ov = SWZF(av, 0x401F); int oi = __builtin_amdgcn_ds_swizzle(ai, 0x401F);
        if (ov > av || (ov == av && oi < ai)) { av = ov; ai = oi; }
        S  = __fadd_rn(S,  SWZF(S,  0x401F));
        px = __fadd_rn(px, SWZF(px, 0x401F));
        py = __fadd_rn(py, SWZF(py, 0x401F));
      }
      {
        float ov = __shfl_xor(av, 32, 64); int oi = __shfl_xor(ai, 32, 64);
        if (ov > av || (ov == av && oi < ai)) { av = ov; ai = oi; }
        S  = __fadd_rn(S,  __shfl_xor(S,  32, 64));
        px = __fadd_rn(px, __shfl_xor(px, 32, 64));
        py = __fadd_rn(py, __shfl_xor(py, 32, 64));
      }
      if (lane == 0) {
        wredA[wv] = make_float2(av, (float)ai);
        wredB[wv] = make_float4(S, px, py, 0.0f);
      }
    }
    __syncthreads();                               // b3
    // ---- FG: packed final combine, state update, h_new ----
    {
      float2 a0c = wredA[0];
      float bv = a0c.x; int bi = (int)a0c.y;
#pragma unroll
      for (int w = 1; w < 8; ++w) {
        float2 aw = wredA[w];
        if (aw.x > bv) { bv = aw.x; bi = (int)aw.y; }
      }
      int ni = bi;
      float4 b0 = wredB[0];
      float S = b0.x, px = b0.y, py = b0.z;
#pragma unroll
      for (int w = 1; w < 8; ++w) {
        float4 bw = wredB[w];
        S = __fadd_rn(S, bw.x); px = __fadd_rn(px, bw.y); py = __fadd_rn(py, bw.z);
      }
      float dis = drowX[ni];
      float fl = __fsub_rn(fuelR, __fmul_rn(0.2f, dis));
      float tm = __fsub_rn(timeR, __fdiv_rn(dis, 60.0f));
      if (ni <= 3) fl = 60.0f;
      if (ni == 0) tm = 11.0f;
      fuelR = fl; timeR = tm;
      if (s == ni && ni > 3) demreg = 0.0f;
      float2 dxy = xy2[ni];
      decxR = dxy.x; decyR = dxy.y;
      prevPr = __fdiv_rn(pe, S);
      prevLp = __fsub_rn(lg, fast_ln(S));
      prevNi = ni;
      if (tid < HD) {
        float cx = __fdiv_rn(px, S), cy = __fdiv_rn(py, S);
        float ctxd = fmaf(C0a[tid], cx, fmaf(C1a[tid], cy, C2a[tid]));
        float val = __fadd_rn(__fadd_rn(ctxd, wc2v[tid]), bca[tid]);
        hstm[tid] = fast_tanh(val);
      }
      niR = ni;
    }
    __syncthreads();                               // b4
  }
  // final step's outputs
  if (hf == 0) out_probs[((size_t)b * T + (T - 1)) * SEQN + s] = prevPr;
  if (s == prevNi && hf == 0) {
    out_tours[(size_t)b * T + (T - 1)] = (float)prevNi;
    out_logps[(size_t)b * T + (T - 1)] = prevLp;
  }
}

extern "C" void kernel_launch(void* const* d_in, const int* in_sizes, int n_in,
                              void* d_out, int out_size, void* d_ws, size_t ws_size,
                              hipStream_t stream) {
  (void)in_sizes; (void)n_in; (void)out_size; (void)d_ws; (void)ws_size;
  (void)hipFuncSetAttribute((const void*)evrp_kernel,
                            hipFuncAttributeMaxDynamicSharedMemorySize,
                            SEQN * HD * 4);
  evrp_kernel<<<dim3(BSZ), dim3(512), SEQN * HD * 4, stream>>>(
      (const float*)d_in[0],  (const float*)d_in[1],  (const float*)d_in[2],
      (const float*)d_in[3],  (const float*)d_in[4],  (const float*)d_in[5],
      (const float*)d_in[6],  (const float*)d_in[7],  (const float*)d_in[8],
      (const float*)d_in[9],  (const float*)d_in[10], (const float*)d_in[11],
      (const float*)d_in[12], (const float*)d_in[13], (const float*)d_in[14],
      (const int*)d_in[15],   (float*)d_out);
}